// Round 9
// baseline (4401.484 us; speedup 1.0000x reference)
//
#include <hip/hip_runtime.h>
#include <hip/hip_bf16.h>
#include <math.h>

// Problem constants (fixed by reference: x,y are (4096, 512) fp32)
#define N 4096
#define D 512

// log-domain constants (base-2 internally; v_exp_f32/v_log_f32 are base-2)
#define K_LOG2 14.426950408889634f          // (1/eps) * log2(e), eps = 0.1
#define TWO_K  28.853900817779268f          // 2 * K_LOG2
#define NEG_EPS_LN2 (-0.06931471805599453f) // -eps * ln(2)
#define EPS_NEG_LOGMU 0.8317766166719343f   // -eps * log_mu = eps * log(4096)

// Sparse-candidate machinery (R5-R7 proven): entries with u < rowmax - MARGIN
// contribute < 2^-MARGIN; MARGIN=600 covers inter-build potential drift with
// >10x headroom (absmax 0.0 across R5-R7).
#define CAP 512
#define MARGIN 600.0f
#define PBLOCKS 192   // <=256 blocks: all co-resident by construction (>=1 blk/CU)

typedef __bf16   bf16x8 __attribute__((ext_vector_type(8)));
typedef _Float16 halfx8 __attribute__((ext_vector_type(8)));
typedef float    floatx4 __attribute__((ext_vector_type(4)));
typedef unsigned short ushortx8v __attribute__((ext_vector_type(8)));

// ---------- fused prep: fp32 -> bf16 rows + exact fp32 row sqnorms ----------
// 2048 blocks x 256: wave w handles row blockIdx.x*4+w of the 8192 (x then y).
__global__ __launch_bounds__(256) void prep_kernel(
    const float* __restrict__ x, const float* __restrict__ y,
    __bf16* __restrict__ xb, __bf16* __restrict__ yb,
    float* __restrict__ x2, float* __restrict__ y2) {
    int wave = threadIdx.x >> 6, lane = threadIdx.x & 63;
    int r = blockIdx.x * 4 + wave;            // 0..8191
    const float* src = (r < N) ? x + (size_t)r * D : y + (size_t)(r - N) * D;
    __bf16* dst      = (r < N) ? xb + (size_t)r * D : yb + (size_t)(r - N) * D;
    float* sq        = (r < N) ? x2 + r : y2 + (r - N);
    floatx4 a = *(const floatx4*)(src + lane * 8);
    floatx4 b = *(const floatx4*)(src + lane * 8 + 4);
    bf16x8 v;
    float acc = 0.f;
#pragma unroll
    for (int k = 0; k < 4; k++) {
        v[k] = (__bf16)a[k]; v[4 + k] = (__bf16)b[k];
        acc += a[k] * a[k] + b[k] * b[k];
    }
    *(bf16x8*)(dst + lane * 8) = v;
    for (int off = 32; off > 0; off >>= 1) acc += __shfl_down(acc, off);
    if (lane == 0) *sq = acc;
}

// ---------- 128x128-tile GEMM: out = A @ B^T (fp16), writes tile + transposed tile ----------
// (round-4 proven; sym=1 computes upper-triangle blocks + mirror writes)
__global__ __launch_bounds__(256) void gemm128_kernel(
    const __bf16* __restrict__ A, const __bf16* __restrict__ Bm,
    _Float16* __restrict__ out1, _Float16* __restrict__ out2, int sym) {
    if (sym && blockIdx.x > blockIdx.y) return;
    __shared__ char smem[34816];
    __bf16* ldsA = (__bf16*)smem;           // [128][64] swizzled
    __bf16* ldsB = ldsA + 128 * 64;

    int t = threadIdx.x;
    int w = t >> 6, lane = t & 63;
    int m = lane & 15, q = lane >> 4;
    int wr = w & 1, wc = w >> 1;
    int m0 = blockIdx.x * 128, n0 = blockIdx.y * 128;

    int srow = t >> 1, shalf = t & 1;
    const bf16x8* gA = (const bf16x8*)(A  + (size_t)(m0 + srow) * D + shalf * 32);
    const bf16x8* gB = (const bf16x8*)(Bm + (size_t)(n0 + srow) * D + shalf * 32);

    floatx4 acc[4][4];
#pragma unroll
    for (int i = 0; i < 4; i++)
#pragma unroll
        for (int j = 0; j < 4; j++) acc[i][j] = (floatx4){0.f, 0.f, 0.f, 0.f};

    for (int slab = 0; slab < 8; slab++) {
        bf16x8 va[4], vb[4];
#pragma unroll
        for (int i = 0; i < 4; i++) {
            va[i] = gA[slab * 8 + i];
            vb[i] = gB[slab * 8 + i];
        }
        __syncthreads();
#pragma unroll
        for (int i = 0; i < 4; i++) {
            int cp = (shalf * 4 + i) ^ (srow & 7);
            *(bf16x8*)(ldsA + srow * 64 + cp * 8) = va[i];
            *(bf16x8*)(ldsB + srow * 64 + cp * 8) = vb[i];
        }
        __syncthreads();
#pragma unroll
        for (int kk = 0; kk < 2; kk++) {
            bf16x8 af[4], bfr[4];
#pragma unroll
            for (int mt = 0; mt < 4; mt++) {
                int cp = (kk * 4 + q) ^ (m & 7);
                af[mt]  = *(const bf16x8*)(ldsA + (wr * 64 + mt * 16 + m) * 64 + cp * 8);
                bfr[mt] = *(const bf16x8*)(ldsB + (wc * 64 + mt * 16 + m) * 64 + cp * 8);
            }
#pragma unroll
            for (int mt = 0; mt < 4; mt++)
#pragma unroll
                for (int nt = 0; nt < 4; nt++)
                    acc[mt][nt] = __builtin_amdgcn_mfma_f32_16x16x32_bf16(
                        af[mt], bfr[nt], acc[mt][nt], 0, 0, 0);
        }
    }

    __syncthreads();
    _Float16* et = (_Float16*)smem + w * (64 * 66);
#pragma unroll
    for (int mt = 0; mt < 4; mt++)
#pragma unroll
        for (int nt = 0; nt < 4; nt++)
#pragma unroll
            for (int r = 0; r < 4; r++)
                et[(mt * 16 + q * 4 + r) * 66 + nt * 16 + m] = (_Float16)acc[mt][nt][r];

    int l3 = lane >> 3, c8 = lane & 7;
#pragma unroll
    for (int rr = 0; rr < 8; rr++) {
        int rl = rr * 8 + l3;
        halfx8 v = *(const halfx8*)(et + rl * 66 + c8 * 8);
        *(halfx8*)(out1 + (size_t)(m0 + wr * 64 + rl) * N + n0 + wc * 64 + c8 * 8) = v;
    }
#pragma unroll
    for (int rr = 0; rr < 8; rr++) {
        int rT = rr * 8 + l3;
        halfx8 v;
#pragma unroll
        for (int k = 0; k < 8; k++) v[k] = et[(c8 * 8 + k) * 66 + rT];
        *(halfx8*)(out2 + (size_t)(n0 + wc * 64 + rT) * N + m0 + wr * 64 + c8 * 8) = v;
    }
}

// ---------- full Sinkhorn pass (R7-proven): 3 pairs, 1 row/wave, 3072 blocks ----------
// gykT transposed in LDS -> conflict-free lane-consecutive reads.
// BUILD=1: ballot compaction with chunk-level skip; writes cnt[idx]=ncand.
template<int BUILD>
__global__ __launch_bounds__(256) void lse_full3_kernel(
    const _Float16* __restrict__ Sxy, const _Float16* __restrict__ STxy,
    const _Float16* __restrict__ Sxx, const _Float16* __restrict__ Syy,
    const float* __restrict__ x2, const float* __restrict__ y2,
    float* __restrict__ Pxy0, float* __restrict__ Pxy1,
    float* __restrict__ Pxx0, float* __restrict__ Pxx1,
    float* __restrict__ Pyy0, float* __restrict__ Pyy1,
    int odd,
    unsigned int* __restrict__ cand, int* __restrict__ cnt,
    float* __restrict__ prevmax) {
    __shared__ float gykT[8 * 512];
    int pair = blockIdx.x >> 10;
    int blk = blockIdx.x & 1023;
    const _Float16* M;
    const float *own, *other, *pin;
    float* pout;
    if (pair == 0) {
        if (odd) { M = Sxy;  own = x2; other = y2; pin = Pxy0; pout = Pxy1; }
        else     { M = STxy; own = y2; other = x2; pin = Pxy1; pout = Pxy0; }
    } else if (pair == 1) {
        M = Sxx; own = x2; other = x2;
        if (odd) { pin = Pxx0; pout = Pxx1; } else { pin = Pxx1; pout = Pxx0; }
    } else {
        M = Syy; own = y2; other = y2;
        if (odd) { pin = Pyy0; pout = Pyy1; } else { pin = Pyy1; pout = Pyy0; }
    }

    int wave = threadIdx.x >> 6, lane = threadIdx.x & 63;

    {   // stage gykT[(j&7)*512 + (j>>3)] = (pin[j] - other[j]) * K
        const floatx4* pi4 = (const floatx4*)pin;
        const floatx4* so4 = (const floatx4*)other;
        for (int tt = threadIdx.x; tt < N / 4; tt += 256) {
            floatx4 pv = pi4[tt], ov = so4[tt];
            int j = tt * 4;
#pragma unroll
            for (int k2 = 0; k2 < 4; k2++) {
                int jj = j + k2;
                gykT[(jj & 7) * 512 + (jj >> 3)] = (pv[k2] - ov[k2]) * K_LOG2;
            }
        }
    }
    __syncthreads();

    int row = blk * 4 + wave;
    int set = pair * 2 + (odd ? 0 : 1);
    int idx = set * N + row;
    float thr = 0.f;
    size_t cbase = 0;
    int ncand = 0;
    unsigned long long lt_mask = (1ull << lane) - 1ull;
    if (BUILD) { thr = prevmax[idx] - MARGIN; cbase = (size_t)idx * CAP; }

    const halfx8* srow = (const halfx8*)(M + (size_t)row * N);
    float m = -INFINITY, s = 0.f;
#pragma unroll
    for (int c = 0; c < 8; c++) {
        int chunk = c * 64 + lane;
        halfx8 sv = srow[chunk];
        int j0 = chunk * 8;
        float u[8];
#pragma unroll
        for (int k = 0; k < 8; k++)
            u[k] = fmaf((float)sv[k], TWO_K, gykT[k * 512 + chunk]);
        float mloc = fmaxf(fmaxf(fmaxf(u[0], u[1]), fmaxf(u[2], u[3])),
                           fmaxf(fmaxf(u[4], u[5]), fmaxf(u[6], u[7])));
        if (BUILD) {
            if (__ballot(mloc >= thr)) {
                ushortx8v s8 = __builtin_bit_cast(ushortx8v, sv);
#pragma unroll
                for (int k = 0; k < 8; k++) {
                    bool hit = (u[k] >= thr);
                    unsigned long long mask = __ballot(hit);
                    if (hit) {
                        int slot = ncand + __popcll(mask & lt_mask);
                        if (slot < CAP)
                            cand[cbase + slot] = ((unsigned int)(j0 + k) << 16) | (unsigned int)s8[k];
                    }
                    ncand += (int)__popcll(mask);
                }
            }
        }
        float M2 = fmaxf(m, mloc);
        float acc = 0.f;
#pragma unroll
        for (int k = 0; k < 8; k++) acc += exp2f(u[k] - M2);
        s = s * exp2f(m - M2) + acc;
        m = M2;
    }
    for (int off = 32; off > 0; off >>= 1) {
        float m2 = __shfl_down(m, off), s2 = __shfl_down(s, off);
        float Mx = fmaxf(m, m2);
        s = s * exp2f(m - Mx) + s2 * exp2f(m2 - Mx);
        m = Mx;
    }
    if (lane == 0) {
        pout[row] = NEG_EPS_LN2 * (m + __log2f(s) - own[row] * K_LOG2) + EPS_NEG_LOGMU;
        prevmax[idx] = m;
        if (BUILD) cnt[idx] = ncand;
    }
}

// ================= persistent sparse window (hand-rolled grid barrier) =================
// 192 blocks (<=256 -> all co-resident, no occupancy dependence). 64 blocks/pair,
// 64 rows/block, half-wave (32 lanes) per row -> 2 rows in flight per wave.
// Barrier: monotonic counter, device-scope atomics (m20), agent-scope fences
// (release writeback / acquire invalidate across non-coherent XCD L2s).
__global__ __launch_bounds__(256) void sparse_persist_kernel(
    const _Float16* __restrict__ Sxy, const _Float16* __restrict__ STxy,
    const _Float16* __restrict__ Sxx, const _Float16* __restrict__ Syy,
    const float* __restrict__ x2, const float* __restrict__ y2,
    float* __restrict__ P0, float* __restrict__ P1,
    float* __restrict__ P2, float* __restrict__ P3,
    float* __restrict__ P4, float* __restrict__ P5,
    const unsigned int* __restrict__ cand, const int* __restrict__ cnt,
    float* __restrict__ prevmax,
    int p0, int npass, int* __restrict__ bar, int do_final, float* __restrict__ out)
{
    __shared__ float sb[256];
    const int pair = blockIdx.x >> 6;      // 64 blocks per pair
    const int pblk = blockIdx.x & 63;      // rows pblk*64 .. +63
    const int wave = threadIdx.x >> 6, lane = threadIdx.x & 63;
    const int half = lane >> 5, hl = lane & 31;

    const float* sqa = (pair == 2) ? y2 : x2;
    const float* sqb = (pair == 1) ? x2 : y2;
    const _Float16* Mrow = (pair == 0) ? Sxy : (pair == 1 ? Sxx : Syy);
    const _Float16* Mcol = (pair == 0) ? STxy : Mrow;
    float* PA = (pair == 0) ? P0 : (pair == 1 ? P2 : P4);   // g buffer
    float* PB = (pair == 0) ? P1 : (pair == 1 ? P3 : P5);   // f buffer

    int bt = 0;
    for (int pi = 0; pi < npass; pi++) {
        int p = p0 + pi;
        int odd = p & 1;
        const _Float16* M  = odd ? Mrow : Mcol;
        const float* own   = odd ? sqa : sqb;
        const float* other = odd ? sqb : sqa;
        const float* pin   = odd ? PA : PB;
        float* pout        = odd ? PB : PA;
        int set = pair * 2 + (odd ? 0 : 1);

        for (int i = 0; i < 16; i += 2) {
            int row = pblk * 64 + wave * 16 + i + half;
            int idx = set * N + row;
            int c = cnt[idx];
            float m = -INFINITY, s = 0.f;
            if (c >= 1 && c <= CAP) {
                size_t cbase = (size_t)idx * CAP;
                for (int b = 0; b * 32 < c; b++) {
                    int t = b * 32 + hl;
                    if (t < c) {
                        unsigned int pk = cand[cbase + t];
                        int j = pk >> 16;
                        _Float16 h = __builtin_bit_cast(_Float16, (unsigned short)(pk & 0xffffu));
                        float u = fmaf((float)h, TWO_K, (pin[j] - other[j]) * K_LOG2);
                        if (u <= m) {
                            s += exp2f(u - m);
                        } else {
                            s = s * exp2f(m - u) + 1.f;
                            m = u;
                        }
                    }
                }
            } else {
                // dense fallback with half-wave (rare; correctness safety valve)
                const halfx8* rowp = (const halfx8*)(M + (size_t)row * N);
                for (int ch = hl; ch < N / 8; ch += 32) {
                    halfx8 sv = rowp[ch];
                    int j0 = ch * 8;
                    floatx4 pp0 = *(const floatx4*)(pin + j0);
                    floatx4 pp1 = *(const floatx4*)(pin + j0 + 4);
                    floatx4 oo0 = *(const floatx4*)(other + j0);
                    floatx4 oo1 = *(const floatx4*)(other + j0 + 4);
                    float u[8];
#pragma unroll
                    for (int k = 0; k < 4; k++) {
                        u[k]     = fmaf((float)sv[k],     TWO_K, (pp0[k] - oo0[k]) * K_LOG2);
                        u[k + 4] = fmaf((float)sv[k + 4], TWO_K, (pp1[k] - oo1[k]) * K_LOG2);
                    }
                    float mloc = fmaxf(fmaxf(fmaxf(u[0], u[1]), fmaxf(u[2], u[3])),
                                       fmaxf(fmaxf(u[4], u[5]), fmaxf(u[6], u[7])));
                    float M2 = fmaxf(m, mloc);
                    float acc = 0.f;
#pragma unroll
                    for (int k = 0; k < 8; k++) acc += exp2f(u[k] - M2);
                    s = s * exp2f(m - M2) + acc;
                    m = M2;
                }
            }
            // half-wave merge (offs 16..1 stay within the 32-lane half)
            for (int off = 16; off > 0; off >>= 1) {
                float m2 = __shfl_xor(m, off), s2 = __shfl_xor(s, off);
                float Mx = fmaxf(m, m2);
                float a1 = (m  == -INFINITY) ? 0.f : s  * exp2f(m  - Mx);
                float a2 = (m2 == -INFINITY) ? 0.f : s2 * exp2f(m2 - Mx);
                m = Mx; s = a1 + a2;
            }
            if (hl == 0) {
                pout[row] = NEG_EPS_LN2 * (m + __log2f(s) - own[row] * K_LOG2)
                            + EPS_NEG_LOGMU;
                prevmax[idx] = m;
            }
        }

        // ---- grid barrier: release fence by every thread, monotone counter ----
        __threadfence();
        __syncthreads();
        bt += PBLOCKS;
        if (threadIdx.x == 0) {
            __hip_atomic_fetch_add(bar, 1, __ATOMIC_RELEASE, __HIP_MEMORY_SCOPE_AGENT);
            while (__hip_atomic_load(bar, __ATOMIC_ACQUIRE, __HIP_MEMORY_SCOPE_AGENT) < bt)
                __builtin_amdgcn_s_sleep(1);
            __threadfence();
        }
        __syncthreads();
    }

    if (do_final && blockIdx.x == 0) {
        float s = 0.f;
        for (int t = threadIdx.x; t < N; t += 256)
            s += (P1[t] + P0[t]) - 0.5f * (P3[t] + P2[t]) - 0.5f * (P5[t] + P4[t]);
        sb[threadIdx.x] = s;
        __syncthreads();
        for (int off = 128; off > 0; off >>= 1) {
            if (threadIdx.x < off) sb[threadIdx.x] += sb[threadIdx.x + off];
            __syncthreads();
        }
        if (threadIdx.x == 0) {
            float v = sb[0] * (1.0f / 4096.0f);
            out[0] = v > 0.f ? v : 0.f;
        }
    }
}

// ---------- finalize (fallback path) ----------
__global__ void finalize_kernel(const float* __restrict__ fxy, const float* __restrict__ gxy,
                                const float* __restrict__ fxx, const float* __restrict__ gxx,
                                const float* __restrict__ fyy, const float* __restrict__ gyy,
                                float* __restrict__ out) {
    __shared__ float sb[256];
    float s = 0.f;
    for (int t = threadIdx.x; t < N; t += 256)
        s += (fxy[t] + gxy[t]) - 0.5f * (fxx[t] + gxx[t]) - 0.5f * (fyy[t] + gyy[t]);
    sb[threadIdx.x] = s;
    __syncthreads();
    for (int off = 128; off > 0; off >>= 1) {
        if (threadIdx.x < off) sb[threadIdx.x] += sb[threadIdx.x + off];
        __syncthreads();
    }
    if (threadIdx.x == 0) {
        float v = sb[0] * (1.0f / 4096.0f);
        out[0] = v > 0.f ? v : 0.f;
    }
}

extern "C" void kernel_launch(void* const* d_in, const int* in_sizes, int n_in,
                              void* d_out, int out_size, void* d_ws, size_t ws_size,
                              hipStream_t stream) {
    const float* x = (const float*)d_in[0];
    const float* y = (const float*)d_in[1];

    const size_t SZ_S = (size_t)N * N * sizeof(_Float16);   // 32 MiB
    const size_t SZ_B = (size_t)N * D * sizeof(__bf16);     // 4 MiB
    const size_t SZ_CAND = (size_t)6 * N * CAP * sizeof(unsigned int);  // 48 MiB

    char* w = (char*)d_ws;
    _Float16* Sxy  = (_Float16*)w; w += SZ_S;
    _Float16* STxy = (_Float16*)w; w += SZ_S;
    _Float16* Sxx  = (_Float16*)w; w += SZ_S;
    _Float16* Syy  = (_Float16*)w; w += SZ_S;
    __bf16* xb = (__bf16*)w;       w += SZ_B;
    __bf16* yb = (__bf16*)w;       w += SZ_B;
    int* cnt = (int*)w;            w += (size_t)6 * N * sizeof(int);
    float* prevmax = (float*)w;    w += (size_t)6 * N * sizeof(float);
    float* x2 = (float*)w;         w += N * sizeof(float);
    float* y2 = (float*)w;         w += N * sizeof(float);
    float* P[6];
    for (int i = 0; i < 6; i++) { P[i] = (float*)w; w += N * sizeof(float); }
    int* bar = (int*)w;            w += 4 * sizeof(int);   // bar[0], bar[1]
    unsigned int* cand = (unsigned int*)w; w += SZ_CAND;

    const size_t need = (size_t)(w - (char*)d_ws);
    const bool sparse_ok = (ws_size >= need);

    prep_kernel<<<2048, 256, 0, stream>>>(x, y, xb, yb, x2, y2);

    gemm128_kernel<<<dim3(32, 32), 256, 0, stream>>>(xb, yb, Sxy, STxy, 0);
    gemm128_kernel<<<dim3(32, 32), 256, 0, stream>>>(xb, xb, Sxx, Sxx, 1);
    gemm128_kernel<<<dim3(32, 32), 256, 0, stream>>>(yb, yb, Syy, Syy, 1);

    // zero P[0..5] (6N floats, contiguous) + bar[0..3] right after
    hipMemsetAsync(P[0], 0, (size_t)6 * N * sizeof(float) + 4 * sizeof(int), stream);

    if (sparse_ok) {
        // fulls p=1..8
        for (int p = 1; p <= 8; p++)
            lse_full3_kernel<0><<<3 * (N / 4), 256, 0, stream>>>(
                Sxy, STxy, Sxx, Syy, x2, y2,
                P[0], P[1], P[2], P[3], P[4], P[5], p & 1, cand, cnt, prevmax);
        // builds p=9,10
        for (int p = 9; p <= 10; p++)
            lse_full3_kernel<1><<<3 * (N / 4), 256, 0, stream>>>(
                Sxy, STxy, Sxx, Syy, x2, y2,
                P[0], P[1], P[2], P[3], P[4], P[5], p & 1, cand, cnt, prevmax);
        // sparse window 1: passes 11..48
        sparse_persist_kernel<<<PBLOCKS, 256, 0, stream>>>(
            Sxy, STxy, Sxx, Syy, x2, y2,
            P[0], P[1], P[2], P[3], P[4], P[5],
            cand, cnt, prevmax, 11, 38, bar + 0, 0, (float*)d_out);
        // rebuild p=49,50
        for (int p = 49; p <= 50; p++)
            lse_full3_kernel<1><<<3 * (N / 4), 256, 0, stream>>>(
                Sxy, STxy, Sxx, Syy, x2, y2,
                P[0], P[1], P[2], P[3], P[4], P[5], p & 1, cand, cnt, prevmax);
        // sparse window 2: passes 51..100, finalize inside
        sparse_persist_kernel<<<PBLOCKS, 256, 0, stream>>>(
            Sxy, STxy, Sxx, Syy, x2, y2,
            P[0], P[1], P[2], P[3], P[4], P[5],
            cand, cnt, prevmax, 51, 50, bar + 1, 1, (float*)d_out);
    } else {
        // dense multi-launch fallback (R7-proven shape)
        for (int p = 1; p <= 100; p++)
            lse_full3_kernel<0><<<3 * (N / 4), 256, 0, stream>>>(
                Sxy, STxy, Sxx, Syy, x2, y2,
                P[0], P[1], P[2], P[3], P[4], P[5], p & 1, cand, cnt, prevmax);
        finalize_kernel<<<1, 256, 0, stream>>>(P[1], P[0], P[3], P[2], P[5], P[4],
                                               (float*)d_out);
    }
}

// Round 10
// 3425.558 us; speedup vs baseline: 1.2849x; 1.2849x over previous
//
#include <hip/hip_runtime.h>
#include <hip/hip_bf16.h>
#include <math.h>

// Problem constants (fixed by reference: x,y are (4096, 512) fp32)
#define N 4096
#define D 512

// log-domain constants (base-2 internally; v_exp_f32/v_log_f32 are base-2)
#define K_LOG2 14.426950408889634f          // (1/eps) * log2(e), eps = 0.1
#define TWO_K  28.853900817779268f          // 2 * K_LOG2
#define NEG_EPS_LN2 (-0.06931471805599453f) // -eps * ln(2)
#define EPS_NEG_LOGMU 0.8317766166719343f   // -eps * log_mu = eps * log(4096)

// Sparse-candidate machinery (R5-R7 proven): entries with u < rowmax - MARGIN
// contribute < 2^-MARGIN; MARGIN=600 covers inter-build potential drift with
// >10x headroom (absmax 0.0 across R5-R9).
#define CAP 512
#define MARGIN 600.0f
#define PBLOCKS 768   // 3 blocks/CU (8/CU capacity) -> co-resident by construction

typedef __bf16   bf16x8 __attribute__((ext_vector_type(8)));
typedef _Float16 halfx8 __attribute__((ext_vector_type(8)));
typedef float    floatx4 __attribute__((ext_vector_type(4)));
typedef unsigned short ushortx8v __attribute__((ext_vector_type(8)));

// System-scope (sc0 sc1, cache-bypassing, IF-coherent) access helpers.
// Key CDNA4 lesson from R9: agent-scope fences writeback+invalidate per-XCD
// L2s (5.6 GB/window refetch). These relaxed system atomics move ONLY the
// potentials through the coherent point; read-only data stays L2-cached.
__device__ __forceinline__ float sysloadf(const float* p) {
    return __hip_atomic_load(p, __ATOMIC_RELAXED, __HIP_MEMORY_SCOPE_SYSTEM);
}
__device__ __forceinline__ void sysstoref(float* p, float v) {
    __hip_atomic_store(p, v, __ATOMIC_RELAXED, __HIP_MEMORY_SCOPE_SYSTEM);
}

// ---------- fused prep: fp32 -> bf16 rows + exact fp32 row sqnorms ----------
__global__ __launch_bounds__(256) void prep_kernel(
    const float* __restrict__ x, const float* __restrict__ y,
    __bf16* __restrict__ xb, __bf16* __restrict__ yb,
    float* __restrict__ x2, float* __restrict__ y2) {
    int wave = threadIdx.x >> 6, lane = threadIdx.x & 63;
    int r = blockIdx.x * 4 + wave;            // 0..8191
    const float* src = (r < N) ? x + (size_t)r * D : y + (size_t)(r - N) * D;
    __bf16* dst      = (r < N) ? xb + (size_t)r * D : yb + (size_t)(r - N) * D;
    float* sq        = (r < N) ? x2 + r : y2 + (r - N);
    floatx4 a = *(const floatx4*)(src + lane * 8);
    floatx4 b = *(const floatx4*)(src + lane * 8 + 4);
    bf16x8 v;
    float acc = 0.f;
#pragma unroll
    for (int k = 0; k < 4; k++) {
        v[k] = (__bf16)a[k]; v[4 + k] = (__bf16)b[k];
        acc += a[k] * a[k] + b[k] * b[k];
    }
    *(bf16x8*)(dst + lane * 8) = v;
    for (int off = 32; off > 0; off >>= 1) acc += __shfl_down(acc, off);
    if (lane == 0) *sq = acc;
}

// ---------- 128x128-tile GEMM: out = A @ B^T (fp16), writes tile + transposed tile ----------
// (round-4 proven; sym=1 computes upper-triangle blocks + mirror writes)
__global__ __launch_bounds__(256) void gemm128_kernel(
    const __bf16* __restrict__ A, const __bf16* __restrict__ Bm,
    _Float16* __restrict__ out1, _Float16* __restrict__ out2, int sym) {
    if (sym && blockIdx.x > blockIdx.y) return;
    __shared__ char smem[34816];
    __bf16* ldsA = (__bf16*)smem;           // [128][64] swizzled
    __bf16* ldsB = ldsA + 128 * 64;

    int t = threadIdx.x;
    int w = t >> 6, lane = t & 63;
    int m = lane & 15, q = lane >> 4;
    int wr = w & 1, wc = w >> 1;
    int m0 = blockIdx.x * 128, n0 = blockIdx.y * 128;

    int srow = t >> 1, shalf = t & 1;
    const bf16x8* gA = (const bf16x8*)(A  + (size_t)(m0 + srow) * D + shalf * 32);
    const bf16x8* gB = (const bf16x8*)(Bm + (size_t)(n0 + srow) * D + shalf * 32);

    floatx4 acc[4][4];
#pragma unroll
    for (int i = 0; i < 4; i++)
#pragma unroll
        for (int j = 0; j < 4; j++) acc[i][j] = (floatx4){0.f, 0.f, 0.f, 0.f};

    for (int slab = 0; slab < 8; slab++) {
        bf16x8 va[4], vb[4];
#pragma unroll
        for (int i = 0; i < 4; i++) {
            va[i] = gA[slab * 8 + i];
            vb[i] = gB[slab * 8 + i];
        }
        __syncthreads();
#pragma unroll
        for (int i = 0; i < 4; i++) {
            int cp = (shalf * 4 + i) ^ (srow & 7);
            *(bf16x8*)(ldsA + srow * 64 + cp * 8) = va[i];
            *(bf16x8*)(ldsB + srow * 64 + cp * 8) = vb[i];
        }
        __syncthreads();
#pragma unroll
        for (int kk = 0; kk < 2; kk++) {
            bf16x8 af[4], bfr[4];
#pragma unroll
            for (int mt = 0; mt < 4; mt++) {
                int cp = (kk * 4 + q) ^ (m & 7);
                af[mt]  = *(const bf16x8*)(ldsA + (wr * 64 + mt * 16 + m) * 64 + cp * 8);
                bfr[mt] = *(const bf16x8*)(ldsB + (wc * 64 + mt * 16 + m) * 64 + cp * 8);
            }
#pragma unroll
            for (int mt = 0; mt < 4; mt++)
#pragma unroll
                for (int nt = 0; nt < 4; nt++)
                    acc[mt][nt] = __builtin_amdgcn_mfma_f32_16x16x32_bf16(
                        af[mt], bfr[nt], acc[mt][nt], 0, 0, 0);
        }
    }

    __syncthreads();
    _Float16* et = (_Float16*)smem + w * (64 * 66);
#pragma unroll
    for (int mt = 0; mt < 4; mt++)
#pragma unroll
        for (int nt = 0; nt < 4; nt++)
#pragma unroll
            for (int r = 0; r < 4; r++)
                et[(mt * 16 + q * 4 + r) * 66 + nt * 16 + m] = (_Float16)acc[mt][nt][r];

    int l3 = lane >> 3, c8 = lane & 7;
#pragma unroll
    for (int rr = 0; rr < 8; rr++) {
        int rl = rr * 8 + l3;
        halfx8 v = *(const halfx8*)(et + rl * 66 + c8 * 8);
        *(halfx8*)(out1 + (size_t)(m0 + wr * 64 + rl) * N + n0 + wc * 64 + c8 * 8) = v;
    }
#pragma unroll
    for (int rr = 0; rr < 8; rr++) {
        int rT = rr * 8 + l3;
        halfx8 v;
#pragma unroll
        for (int k = 0; k < 8; k++) v[k] = et[(c8 * 8 + k) * 66 + rT];
        *(halfx8*)(out2 + (size_t)(n0 + wc * 64 + rT) * N + m0 + wr * 64 + c8 * 8) = v;
    }
}

// ---------- full Sinkhorn pass (R7-proven): 3 pairs, 1 row/wave, 3072 blocks ----------
template<int BUILD>
__global__ __launch_bounds__(256) void lse_full3_kernel(
    const _Float16* __restrict__ Sxy, const _Float16* __restrict__ STxy,
    const _Float16* __restrict__ Sxx, const _Float16* __restrict__ Syy,
    const float* __restrict__ x2, const float* __restrict__ y2,
    float* __restrict__ Pxy0, float* __restrict__ Pxy1,
    float* __restrict__ Pxx0, float* __restrict__ Pxx1,
    float* __restrict__ Pyy0, float* __restrict__ Pyy1,
    int odd,
    unsigned int* __restrict__ cand, int* __restrict__ cnt,
    float* __restrict__ prevmax) {
    __shared__ float gykT[8 * 512];
    int pair = blockIdx.x >> 10;
    int blk = blockIdx.x & 1023;
    const _Float16* M;
    const float *own, *other, *pin;
    float* pout;
    if (pair == 0) {
        if (odd) { M = Sxy;  own = x2; other = y2; pin = Pxy0; pout = Pxy1; }
        else     { M = STxy; own = y2; other = x2; pin = Pxy1; pout = Pxy0; }
    } else if (pair == 1) {
        M = Sxx; own = x2; other = x2;
        if (odd) { pin = Pxx0; pout = Pxx1; } else { pin = Pxx1; pout = Pxx0; }
    } else {
        M = Syy; own = y2; other = y2;
        if (odd) { pin = Pyy0; pout = Pyy1; } else { pin = Pyy1; pout = Pyy0; }
    }

    int wave = threadIdx.x >> 6, lane = threadIdx.x & 63;

    {   // stage gykT[(j&7)*512 + (j>>3)] = (pin[j] - other[j]) * K
        const floatx4* pi4 = (const floatx4*)pin;
        const floatx4* so4 = (const floatx4*)other;
        for (int tt = threadIdx.x; tt < N / 4; tt += 256) {
            floatx4 pv = pi4[tt], ov = so4[tt];
            int j = tt * 4;
#pragma unroll
            for (int k2 = 0; k2 < 4; k2++) {
                int jj = j + k2;
                gykT[(jj & 7) * 512 + (jj >> 3)] = (pv[k2] - ov[k2]) * K_LOG2;
            }
        }
    }
    __syncthreads();

    int row = blk * 4 + wave;
    int set = pair * 2 + (odd ? 0 : 1);
    int idx = set * N + row;
    float thr = 0.f;
    size_t cbase = 0;
    int ncand = 0;
    unsigned long long lt_mask = (1ull << lane) - 1ull;
    if (BUILD) { thr = prevmax[idx] - MARGIN; cbase = (size_t)idx * CAP; }

    const halfx8* srow = (const halfx8*)(M + (size_t)row * N);
    float m = -INFINITY, s = 0.f;
#pragma unroll
    for (int c = 0; c < 8; c++) {
        int chunk = c * 64 + lane;
        halfx8 sv = srow[chunk];
        int j0 = chunk * 8;
        float u[8];
#pragma unroll
        for (int k = 0; k < 8; k++)
            u[k] = fmaf((float)sv[k], TWO_K, gykT[k * 512 + chunk]);
        float mloc = fmaxf(fmaxf(fmaxf(u[0], u[1]), fmaxf(u[2], u[3])),
                           fmaxf(fmaxf(u[4], u[5]), fmaxf(u[6], u[7])));
        if (BUILD) {
            if (__ballot(mloc >= thr)) {
                ushortx8v s8 = __builtin_bit_cast(ushortx8v, sv);
#pragma unroll
                for (int k = 0; k < 8; k++) {
                    bool hit = (u[k] >= thr);
                    unsigned long long mask = __ballot(hit);
                    if (hit) {
                        int slot = ncand + __popcll(mask & lt_mask);
                        if (slot < CAP)
                            cand[cbase + slot] = ((unsigned int)(j0 + k) << 16) | (unsigned int)s8[k];
                    }
                    ncand += (int)__popcll(mask);
                }
            }
        }
        float M2 = fmaxf(m, mloc);
        float acc = 0.f;
#pragma unroll
        for (int k = 0; k < 8; k++) acc += exp2f(u[k] - M2);
        s = s * exp2f(m - M2) + acc;
        m = M2;
    }
    for (int off = 32; off > 0; off >>= 1) {
        float m2 = __shfl_down(m, off), s2 = __shfl_down(s, off);
        float Mx = fmaxf(m, m2);
        s = s * exp2f(m - Mx) + s2 * exp2f(m2 - Mx);
        m = Mx;
    }
    if (lane == 0) {
        pout[row] = NEG_EPS_LN2 * (m + __log2f(s) - own[row] * K_LOG2) + EPS_NEG_LOGMU;
        prevmax[idx] = m;
        if (BUILD) cnt[idx] = ncand;
    }
}

// ================= persistent sparse window, fence-free protocol =================
// 768 blocks x 4 waves; wave owns 4 rows (R7 mapping). Potentials exchanged via
// system-scope relaxed atomics (cache-bypassing); read-only S/cand/cnt stay
// L2-cached across all passes (no invalidation). Barrier: __syncthreads drains
// vmcnt (write-through stores then globally visible) -> relaxed system counter.
__global__ __launch_bounds__(256) void sparse_persist_kernel(
    const _Float16* __restrict__ Sxy, const _Float16* __restrict__ STxy,
    const _Float16* __restrict__ Sxx, const _Float16* __restrict__ Syy,
    const float* __restrict__ x2, const float* __restrict__ y2,
    float* __restrict__ P0, float* __restrict__ P1,
    float* __restrict__ P2, float* __restrict__ P3,
    float* __restrict__ P4, float* __restrict__ P5,
    const unsigned int* __restrict__ cand, const int* __restrict__ cnt,
    float* __restrict__ prevmax,
    int p0, int npass, int* __restrict__ bar, int do_final, float* __restrict__ out)
{
    __shared__ float sb[256];
    const int wave = threadIdx.x >> 6, lane = threadIdx.x & 63;
    const int gwave = blockIdx.x * 4 + wave;   // 0..3071
    const int pair = gwave >> 10;
    const int pwave = gwave & 1023;            // rows pwave*4 .. +3

    const float* sqa = (pair == 2) ? y2 : x2;
    const float* sqb = (pair == 1) ? x2 : y2;
    const _Float16* Mrow = (pair == 0) ? Sxy : (pair == 1 ? Sxx : Syy);
    const _Float16* Mcol = (pair == 0) ? STxy : Mrow;
    float* PA = (pair == 0) ? P0 : (pair == 1 ? P2 : P4);   // g buffer
    float* PB = (pair == 0) ? P1 : (pair == 1 ? P3 : P5);   // f buffer

    int bt = 0;
    for (int pi = 0; pi < npass; pi++) {
        int p = p0 + pi;
        int odd = p & 1;
        const _Float16* M  = odd ? Mrow : Mcol;
        const float* own   = odd ? sqa : sqb;
        const float* other = odd ? sqb : sqa;
        const float* pin   = odd ? PA : PB;
        float* pout        = odd ? PB : PA;
        int set = pair * 2 + (odd ? 0 : 1);

        for (int i = 0; i < 4; i++) {
            int row = pwave * 4 + i;
            int idx = set * N + row;
            int c = cnt[idx];            // cached (read-only during window)
            float m, s;
            if (c >= 1 && c <= CAP) {
                size_t cbase = (size_t)idx * CAP;
                int nb = (c + 63) >> 6;
                float uu[8];
                float lm = -INFINITY;
#pragma unroll 8
                for (int b = 0; b < 8; b++) {
                    uu[b] = -INFINITY;
                    if (b < nb) {
                        int t = b * 64 + lane;
                        if (t < c) {
                            unsigned int pk = cand[cbase + t];    // cached
                            int j = pk >> 16;
                            _Float16 h = __builtin_bit_cast(_Float16, (unsigned short)(pk & 0xffffu));
                            uu[b] = fmaf((float)h, TWO_K,
                                         (sysloadf(pin + j) - other[j]) * K_LOG2);
                        }
                        lm = fmaxf(lm, uu[b]);
                    }
                }
                for (int off = 32; off > 0; off >>= 1)
                    lm = fmaxf(lm, __shfl_xor(lm, off));
                float ls = 0.f;
#pragma unroll 8
                for (int b = 0; b < 8; b++)
                    if (b < nb) ls += exp2f(uu[b] - lm);   // -inf -> 0
                for (int off = 32; off > 0; off >>= 1)
                    ls += __shfl_xor(ls, off);
                m = lm; s = ls;
            } else {
                // dense fallback: full row scan (rare; safety valve)
                m = -INFINITY; s = 0.f;
                const halfx8* rowp = (const halfx8*)(M + (size_t)row * N);
                for (int ch = lane; ch < N / 8; ch += 64) {
                    halfx8 sv = rowp[ch];
                    int j0 = ch * 8;
                    float u[8];
#pragma unroll
                    for (int k = 0; k < 8; k++)
                        u[k] = fmaf((float)sv[k], TWO_K,
                                    (sysloadf(pin + j0 + k) - other[j0 + k]) * K_LOG2);
                    float mloc = fmaxf(fmaxf(fmaxf(u[0], u[1]), fmaxf(u[2], u[3])),
                                       fmaxf(fmaxf(u[4], u[5]), fmaxf(u[6], u[7])));
                    float M2 = fmaxf(m, mloc);
                    float acc = 0.f;
#pragma unroll
                    for (int k = 0; k < 8; k++) acc += exp2f(u[k] - M2);
                    s = s * exp2f(m - M2) + acc;
                    m = M2;
                }
                for (int off = 32; off > 0; off >>= 1) {
                    float m2 = __shfl_xor(m, off), s2 = __shfl_xor(s, off);
                    float Mx = fmaxf(m, m2);
                    float a1 = (m  == -INFINITY) ? 0.f : s  * exp2f(m  - Mx);
                    float a2 = (m2 == -INFINITY) ? 0.f : s2 * exp2f(m2 - Mx);
                    m = Mx; s = a1 + a2;
                }
            }
            if (lane == 0) {
                sysstoref(&pout[row],
                          NEG_EPS_LN2 * (m + __log2f(s) - own[row] * K_LOG2)
                          + EPS_NEG_LOGMU);
                prevmax[idx] = m;   // consumed only after kernel-end release
            }
        }

        // ---- fence-free grid barrier ----
        __syncthreads();            // drains vmcnt: system stores now visible
        bt += PBLOCKS;
        if (threadIdx.x == 0) {
            __hip_atomic_fetch_add(bar, 1, __ATOMIC_RELAXED, __HIP_MEMORY_SCOPE_SYSTEM);
            while (__hip_atomic_load(bar, __ATOMIC_RELAXED, __HIP_MEMORY_SCOPE_SYSTEM) < bt)
                __builtin_amdgcn_s_sleep(8);
        }
        __syncthreads();
        asm volatile("" ::: "memory");
    }

    if (do_final && blockIdx.x == 0) {
        float s = 0.f;
        for (int t = threadIdx.x; t < N; t += 256)
            s += (sysloadf(P1 + t) + sysloadf(P0 + t))
               - 0.5f * (sysloadf(P3 + t) + sysloadf(P2 + t))
               - 0.5f * (sysloadf(P5 + t) + sysloadf(P4 + t));
        sb[threadIdx.x] = s;
        __syncthreads();
        for (int off = 128; off > 0; off >>= 1) {
            if (threadIdx.x < off) sb[threadIdx.x] += sb[threadIdx.x + off];
            __syncthreads();
        }
        if (threadIdx.x == 0) {
            float v = sb[0] * (1.0f / 4096.0f);
            out[0] = v > 0.f ? v : 0.f;
        }
    }
}

// ---------- finalize (fallback path) ----------
__global__ void finalize_kernel(const float* __restrict__ fxy, const float* __restrict__ gxy,
                                const float* __restrict__ fxx, const float* __restrict__ gxx,
                                const float* __restrict__ fyy, const float* __restrict__ gyy,
                                float* __restrict__ out) {
    __shared__ float sb[256];
    float s = 0.f;
    for (int t = threadIdx.x; t < N; t += 256)
        s += (fxy[t] + gxy[t]) - 0.5f * (fxx[t] + gxx[t]) - 0.5f * (fyy[t] + gyy[t]);
    sb[threadIdx.x] = s;
    __syncthreads();
    for (int off = 128; off > 0; off >>= 1) {
        if (threadIdx.x < off) sb[threadIdx.x] += sb[threadIdx.x + off];
        __syncthreads();
    }
    if (threadIdx.x == 0) {
        float v = sb[0] * (1.0f / 4096.0f);
        out[0] = v > 0.f ? v : 0.f;
    }
}

extern "C" void kernel_launch(void* const* d_in, const int* in_sizes, int n_in,
                              void* d_out, int out_size, void* d_ws, size_t ws_size,
                              hipStream_t stream) {
    const float* x = (const float*)d_in[0];
    const float* y = (const float*)d_in[1];

    const size_t SZ_S = (size_t)N * N * sizeof(_Float16);   // 32 MiB
    const size_t SZ_B = (size_t)N * D * sizeof(__bf16);     // 4 MiB
    const size_t SZ_CAND = (size_t)6 * N * CAP * sizeof(unsigned int);  // 48 MiB

    char* w = (char*)d_ws;
    _Float16* Sxy  = (_Float16*)w; w += SZ_S;
    _Float16* STxy = (_Float16*)w; w += SZ_S;
    _Float16* Sxx  = (_Float16*)w; w += SZ_S;
    _Float16* Syy  = (_Float16*)w; w += SZ_S;
    __bf16* xb = (__bf16*)w;       w += SZ_B;
    __bf16* yb = (__bf16*)w;       w += SZ_B;
    int* cnt = (int*)w;            w += (size_t)6 * N * sizeof(int);
    float* prevmax = (float*)w;    w += (size_t)6 * N * sizeof(float);
    float* x2 = (float*)w;         w += N * sizeof(float);
    float* y2 = (float*)w;         w += N * sizeof(float);
    float* P[6];
    for (int i = 0; i < 6; i++) { P[i] = (float*)w; w += N * sizeof(float); }
    int* bar = (int*)w;            w += 32 * sizeof(int);   // bar[0], bar[8] (line-split)
    unsigned int* cand = (unsigned int*)w; w += SZ_CAND;

    const size_t need = (size_t)(w - (char*)d_ws);
    const bool sparse_ok = (ws_size >= need);

    prep_kernel<<<2048, 256, 0, stream>>>(x, y, xb, yb, x2, y2);

    gemm128_kernel<<<dim3(32, 32), 256, 0, stream>>>(xb, yb, Sxy, STxy, 0);
    gemm128_kernel<<<dim3(32, 32), 256, 0, stream>>>(xb, xb, Sxx, Sxx, 1);
    gemm128_kernel<<<dim3(32, 32), 256, 0, stream>>>(yb, yb, Syy, Syy, 1);

    // zero P[0..5] (6N floats, contiguous) + bar[] right after
    hipMemsetAsync(P[0], 0, (size_t)6 * N * sizeof(float) + 32 * sizeof(int), stream);

    if (sparse_ok) {
        // fulls p=1..8
        for (int p = 1; p <= 8; p++)
            lse_full3_kernel<0><<<3 * (N / 4), 256, 0, stream>>>(
                Sxy, STxy, Sxx, Syy, x2, y2,
                P[0], P[1], P[2], P[3], P[4], P[5], p & 1, cand, cnt, prevmax);
        // builds p=9,10
        for (int p = 9; p <= 10; p++)
            lse_full3_kernel<1><<<3 * (N / 4), 256, 0, stream>>>(
                Sxy, STxy, Sxx, Syy, x2, y2,
                P[0], P[1], P[2], P[3], P[4], P[5], p & 1, cand, cnt, prevmax);
        // sparse window 1: passes 11..48
        sparse_persist_kernel<<<PBLOCKS, 256, 0, stream>>>(
            Sxy, STxy, Sxx, Syy, x2, y2,
            P[0], P[1], P[2], P[3], P[4], P[5],
            cand, cnt, prevmax, 11, 38, bar + 0, 0, (float*)d_out);
        // rebuild p=49,50
        for (int p = 49; p <= 50; p++)
            lse_full3_kernel<1><<<3 * (N / 4), 256, 0, stream>>>(
                Sxy, STxy, Sxx, Syy, x2, y2,
                P[0], P[1], P[2], P[3], P[4], P[5], p & 1, cand, cnt, prevmax);
        // sparse window 2: passes 51..100, finalize inside
        sparse_persist_kernel<<<PBLOCKS, 256, 0, stream>>>(
            Sxy, STxy, Sxx, Syy, x2, y2,
            P[0], P[1], P[2], P[3], P[4], P[5],
            cand, cnt, prevmax, 51, 50, bar + 16, 1, (float*)d_out);
    } else {
        // dense multi-launch fallback (R7-proven shape)
        for (int p = 1; p <= 100; p++)
            lse_full3_kernel<0><<<3 * (N / 4), 256, 0, stream>>>(
                Sxy, STxy, Sxx, Syy, x2, y2,
                P[0], P[1], P[2], P[3], P[4], P[5], p & 1, cand, cnt, prevmax);
        finalize_kernel<<<1, 256, 0, stream>>>(P[1], P[0], P[3], P[2], P[5], P[4],
                                               (float*)d_out);
    }
}

// Round 11
// 1856.883 us; speedup vs baseline: 2.3704x; 1.8448x over previous
//
#include <hip/hip_runtime.h>
#include <hip/hip_bf16.h>
#include <math.h>

// Problem constants (fixed by reference: x,y are (4096, 512) fp32)
#define N 4096
#define D 512

// log-domain constants (base-2 internally; v_exp_f32/v_log_f32 are base-2)
#define K_LOG2 14.426950408889634f          // (1/eps) * log2(e), eps = 0.1
#define TWO_K  28.853900817779268f          // 2 * K_LOG2
#define NEG_EPS_LN2 (-0.06931471805599453f) // -eps * ln(2)
#define EPS_NEG_LOGMU 0.8317766166719343f   // -eps * log_mu = eps * log(4096)

// Sparse-candidate machinery (R5-R10 proven): entries with u < rowmax - MARGIN
// contribute < 2^-MARGIN; MARGIN=600 covers inter-build potential drift with
// >10x headroom (absmax 0.0 across R5-R10).
#define CAP 512
#define MARGIN 600.0f
#define PBLOCKS 384   // 1.5 blocks/CU -> co-resident by construction
#define NCTR 32       // distributed arrival counters (128B apart)
#define GO_OFF 1024   // go-word offset (ints) within a window's bar region
#define BARWIN 2048   // ints per window region

typedef __bf16   bf16x8 __attribute__((ext_vector_type(8)));
typedef _Float16 halfx8 __attribute__((ext_vector_type(8)));
typedef float    floatx4 __attribute__((ext_vector_type(4)));
typedef unsigned short ushortx8v __attribute__((ext_vector_type(8)));

// System-scope (cache-bypassing, IF-coherent) helpers. R9/R10 lessons:
// agent fences writeback+invalidate per-XCD L2s (ruinous); flat single-counter
// barriers serialize 768 RMWs (~35us/pass). Protocol: relaxed system atomics
// for potentials only; hierarchical barrier below.
__device__ __forceinline__ float sysloadf(const float* p) {
    return __hip_atomic_load(p, __ATOMIC_RELAXED, __HIP_MEMORY_SCOPE_SYSTEM);
}
__device__ __forceinline__ void sysstoref(float* p, float v) {
    __hip_atomic_store(p, v, __ATOMIC_RELAXED, __HIP_MEMORY_SCOPE_SYSTEM);
}
__device__ __forceinline__ int sysloadi(const int* p) {
    return __hip_atomic_load(p, __ATOMIC_RELAXED, __HIP_MEMORY_SCOPE_SYSTEM);
}

// ---------- fused prep: fp32 -> bf16 rows + exact fp32 row sqnorms ----------
__global__ __launch_bounds__(256) void prep_kernel(
    const float* __restrict__ x, const float* __restrict__ y,
    __bf16* __restrict__ xb, __bf16* __restrict__ yb,
    float* __restrict__ x2, float* __restrict__ y2) {
    int wave = threadIdx.x >> 6, lane = threadIdx.x & 63;
    int r = blockIdx.x * 4 + wave;            // 0..8191
    const float* src = (r < N) ? x + (size_t)r * D : y + (size_t)(r - N) * D;
    __bf16* dst      = (r < N) ? xb + (size_t)r * D : yb + (size_t)(r - N) * D;
    float* sq        = (r < N) ? x2 + r : y2 + (r - N);
    floatx4 a = *(const floatx4*)(src + lane * 8);
    floatx4 b = *(const floatx4*)(src + lane * 8 + 4);
    bf16x8 v;
    float acc = 0.f;
#pragma unroll
    for (int k = 0; k < 4; k++) {
        v[k] = (__bf16)a[k]; v[4 + k] = (__bf16)b[k];
        acc += a[k] * a[k] + b[k] * b[k];
    }
    *(bf16x8*)(dst + lane * 8) = v;
    for (int off = 32; off > 0; off >>= 1) acc += __shfl_down(acc, off);
    if (lane == 0) *sq = acc;
}

// ---------- 128x128-tile GEMM: out = A @ B^T (fp16), writes tile + transposed tile ----------
// (round-4 proven; sym=1 computes upper-triangle blocks + mirror writes)
__global__ __launch_bounds__(256) void gemm128_kernel(
    const __bf16* __restrict__ A, const __bf16* __restrict__ Bm,
    _Float16* __restrict__ out1, _Float16* __restrict__ out2, int sym) {
    if (sym && blockIdx.x > blockIdx.y) return;
    __shared__ char smem[34816];
    __bf16* ldsA = (__bf16*)smem;           // [128][64] swizzled
    __bf16* ldsB = ldsA + 128 * 64;

    int t = threadIdx.x;
    int w = t >> 6, lane = t & 63;
    int m = lane & 15, q = lane >> 4;
    int wr = w & 1, wc = w >> 1;
    int m0 = blockIdx.x * 128, n0 = blockIdx.y * 128;

    int srow = t >> 1, shalf = t & 1;
    const bf16x8* gA = (const bf16x8*)(A  + (size_t)(m0 + srow) * D + shalf * 32);
    const bf16x8* gB = (const bf16x8*)(Bm + (size_t)(n0 + srow) * D + shalf * 32);

    floatx4 acc[4][4];
#pragma unroll
    for (int i = 0; i < 4; i++)
#pragma unroll
        for (int j = 0; j < 4; j++) acc[i][j] = (floatx4){0.f, 0.f, 0.f, 0.f};

    for (int slab = 0; slab < 8; slab++) {
        bf16x8 va[4], vb[4];
#pragma unroll
        for (int i = 0; i < 4; i++) {
            va[i] = gA[slab * 8 + i];
            vb[i] = gB[slab * 8 + i];
        }
        __syncthreads();
#pragma unroll
        for (int i = 0; i < 4; i++) {
            int cp = (shalf * 4 + i) ^ (srow & 7);
            *(bf16x8*)(ldsA + srow * 64 + cp * 8) = va[i];
            *(bf16x8*)(ldsB + srow * 64 + cp * 8) = vb[i];
        }
        __syncthreads();
#pragma unroll
        for (int kk = 0; kk < 2; kk++) {
            bf16x8 af[4], bfr[4];
#pragma unroll
            for (int mt = 0; mt < 4; mt++) {
                int cp = (kk * 4 + q) ^ (m & 7);
                af[mt]  = *(const bf16x8*)(ldsA + (wr * 64 + mt * 16 + m) * 64 + cp * 8);
                bfr[mt] = *(const bf16x8*)(ldsB + (wc * 64 + mt * 16 + m) * 64 + cp * 8);
            }
#pragma unroll
            for (int mt = 0; mt < 4; mt++)
#pragma unroll
                for (int nt = 0; nt < 4; nt++)
                    acc[mt][nt] = __builtin_amdgcn_mfma_f32_16x16x32_bf16(
                        af[mt], bfr[nt], acc[mt][nt], 0, 0, 0);
        }
    }

    __syncthreads();
    _Float16* et = (_Float16*)smem + w * (64 * 66);
#pragma unroll
    for (int mt = 0; mt < 4; mt++)
#pragma unroll
        for (int nt = 0; nt < 4; nt++)
#pragma unroll
            for (int r = 0; r < 4; r++)
                et[(mt * 16 + q * 4 + r) * 66 + nt * 16 + m] = (_Float16)acc[mt][nt][r];

    int l3 = lane >> 3, c8 = lane & 7;
#pragma unroll
    for (int rr = 0; rr < 8; rr++) {
        int rl = rr * 8 + l3;
        halfx8 v = *(const halfx8*)(et + rl * 66 + c8 * 8);
        *(halfx8*)(out1 + (size_t)(m0 + wr * 64 + rl) * N + n0 + wc * 64 + c8 * 8) = v;
    }
#pragma unroll
    for (int rr = 0; rr < 8; rr++) {
        int rT = rr * 8 + l3;
        halfx8 v;
#pragma unroll
        for (int k = 0; k < 8; k++) v[k] = et[(c8 * 8 + k) * 66 + rT];
        *(halfx8*)(out2 + (size_t)(n0 + wc * 64 + rT) * N + m0 + wr * 64 + c8 * 8) = v;
    }
}

// ---------- full Sinkhorn pass (R7-proven): 3 pairs, 1 row/wave, 3072 blocks ----------
template<int BUILD>
__global__ __launch_bounds__(256) void lse_full3_kernel(
    const _Float16* __restrict__ Sxy, const _Float16* __restrict__ STxy,
    const _Float16* __restrict__ Sxx, const _Float16* __restrict__ Syy,
    const float* __restrict__ x2, const float* __restrict__ y2,
    float* __restrict__ Pxy0, float* __restrict__ Pxy1,
    float* __restrict__ Pxx0, float* __restrict__ Pxx1,
    float* __restrict__ Pyy0, float* __restrict__ Pyy1,
    int odd,
    unsigned int* __restrict__ cand, int* __restrict__ cnt,
    float* __restrict__ prevmax) {
    __shared__ float gykT[8 * 512];
    int pair = blockIdx.x >> 10;
    int blk = blockIdx.x & 1023;
    const _Float16* M;
    const float *own, *other, *pin;
    float* pout;
    if (pair == 0) {
        if (odd) { M = Sxy;  own = x2; other = y2; pin = Pxy0; pout = Pxy1; }
        else     { M = STxy; own = y2; other = x2; pin = Pxy1; pout = Pxy0; }
    } else if (pair == 1) {
        M = Sxx; own = x2; other = x2;
        if (odd) { pin = Pxx0; pout = Pxx1; } else { pin = Pxx1; pout = Pxx0; }
    } else {
        M = Syy; own = y2; other = y2;
        if (odd) { pin = Pyy0; pout = Pyy1; } else { pin = Pyy1; pout = Pyy0; }
    }

    int wave = threadIdx.x >> 6, lane = threadIdx.x & 63;

    {   // stage gykT[(j&7)*512 + (j>>3)] = (pin[j] - other[j]) * K
        const floatx4* pi4 = (const floatx4*)pin;
        const floatx4* so4 = (const floatx4*)other;
        for (int tt = threadIdx.x; tt < N / 4; tt += 256) {
            floatx4 pv = pi4[tt], ov = so4[tt];
            int j = tt * 4;
#pragma unroll
            for (int k2 = 0; k2 < 4; k2++) {
                int jj = j + k2;
                gykT[(jj & 7) * 512 + (jj >> 3)] = (pv[k2] - ov[k2]) * K_LOG2;
            }
        }
    }
    __syncthreads();

    int row = blk * 4 + wave;
    int set = pair * 2 + (odd ? 0 : 1);
    int idx = set * N + row;
    float thr = 0.f;
    size_t cbase = 0;
    int ncand = 0;
    unsigned long long lt_mask = (1ull << lane) - 1ull;
    if (BUILD) { thr = prevmax[idx] - MARGIN; cbase = (size_t)idx * CAP; }

    const halfx8* srow = (const halfx8*)(M + (size_t)row * N);
    float m = -INFINITY, s = 0.f;
#pragma unroll
    for (int c = 0; c < 8; c++) {
        int chunk = c * 64 + lane;
        halfx8 sv = srow[chunk];
        int j0 = chunk * 8;
        float u[8];
#pragma unroll
        for (int k = 0; k < 8; k++)
            u[k] = fmaf((float)sv[k], TWO_K, gykT[k * 512 + chunk]);
        float mloc = fmaxf(fmaxf(fmaxf(u[0], u[1]), fmaxf(u[2], u[3])),
                           fmaxf(fmaxf(u[4], u[5]), fmaxf(u[6], u[7])));
        if (BUILD) {
            if (__ballot(mloc >= thr)) {
                ushortx8v s8 = __builtin_bit_cast(ushortx8v, sv);
#pragma unroll
                for (int k = 0; k < 8; k++) {
                    bool hit = (u[k] >= thr);
                    unsigned long long mask = __ballot(hit);
                    if (hit) {
                        int slot = ncand + __popcll(mask & lt_mask);
                        if (slot < CAP)
                            cand[cbase + slot] = ((unsigned int)(j0 + k) << 16) | (unsigned int)s8[k];
                    }
                    ncand += (int)__popcll(mask);
                }
            }
        }
        float M2 = fmaxf(m, mloc);
        float acc = 0.f;
#pragma unroll
        for (int k = 0; k < 8; k++) acc += exp2f(u[k] - M2);
        s = s * exp2f(m - M2) + acc;
        m = M2;
    }
    for (int off = 32; off > 0; off >>= 1) {
        float m2 = __shfl_down(m, off), s2 = __shfl_down(s, off);
        float Mx = fmaxf(m, m2);
        s = s * exp2f(m - Mx) + s2 * exp2f(m2 - Mx);
        m = Mx;
    }
    if (lane == 0) {
        pout[row] = NEG_EPS_LN2 * (m + __log2f(s) - own[row] * K_LOG2) + EPS_NEG_LOGMU;
        prevmax[idx] = m;
        if (BUILD) cnt[idx] = ncand;
    }
}

// ================= persistent sparse window, hierarchical fence-free barrier =================
// 384 blocks (1.5/CU). 128 blocks/pair; wave owns 8 rows. Potentials via
// relaxed system atomics (cache-bypassing); S/cand/cnt stay L2-cached.
// Barrier: 32 spread arrival counters (<=12 serialized RMWs each) -> leader
// block sums them -> single go-word; pollers read-only (no RMW serialization).
__global__ __launch_bounds__(256) void sparse_persist_kernel(
    const _Float16* __restrict__ Sxy, const _Float16* __restrict__ STxy,
    const _Float16* __restrict__ Sxx, const _Float16* __restrict__ Syy,
    const float* __restrict__ x2, const float* __restrict__ y2,
    float* __restrict__ P0, float* __restrict__ P1,
    float* __restrict__ P2, float* __restrict__ P3,
    float* __restrict__ P4, float* __restrict__ P5,
    const unsigned int* __restrict__ cand, const int* __restrict__ cnt,
    float* __restrict__ prevmax,
    int p0, int npass, int* __restrict__ bar, int do_final, float* __restrict__ out)
{
    __shared__ float sb[256];
    const int wave = threadIdx.x >> 6, lane = threadIdx.x & 63;
    const int pair = blockIdx.x >> 7;          // 128 blocks/pair
    const int pblk = blockIdx.x & 127;         // rows pblk*32 + wave*8 .. +7

    const float* sqa = (pair == 2) ? y2 : x2;
    const float* sqb = (pair == 1) ? x2 : y2;
    const _Float16* Mrow = (pair == 0) ? Sxy : (pair == 1 ? Sxx : Syy);
    const _Float16* Mcol = (pair == 0) ? STxy : Mrow;
    float* PA = (pair == 0) ? P0 : (pair == 1 ? P2 : P4);   // g buffer
    float* PB = (pair == 0) ? P1 : (pair == 1 ? P3 : P5);   // f buffer

    for (int pi = 0; pi < npass; pi++) {
        int p = p0 + pi;
        int odd = p & 1;
        const _Float16* M  = odd ? Mrow : Mcol;
        const float* own   = odd ? sqa : sqb;
        const float* other = odd ? sqb : sqa;
        const float* pin   = odd ? PA : PB;
        float* pout        = odd ? PB : PA;
        int set = pair * 2 + (odd ? 0 : 1);

        for (int i = 0; i < 8; i++) {
            int row = pblk * 32 + wave * 8 + i;
            int idx = set * N + row;
            int c = cnt[idx];            // L2-cached (read-only during window)
            float m, s;
            if (c >= 1 && c <= CAP) {
                size_t cbase = (size_t)idx * CAP;
                int nb = (c + 63) >> 6;
                float uu[8];
                float lm = -INFINITY;
#pragma unroll 8
                for (int b = 0; b < 8; b++) {
                    uu[b] = -INFINITY;
                    if (b < nb) {
                        int t = b * 64 + lane;
                        if (t < c) {
                            unsigned int pk = cand[cbase + t];    // cached
                            int j = pk >> 16;
                            _Float16 h = __builtin_bit_cast(_Float16, (unsigned short)(pk & 0xffffu));
                            uu[b] = fmaf((float)h, TWO_K,
                                         (sysloadf(pin + j) - other[j]) * K_LOG2);
                        }
                        lm = fmaxf(lm, uu[b]);
                    }
                }
                for (int off = 32; off > 0; off >>= 1)
                    lm = fmaxf(lm, __shfl_xor(lm, off));
                float ls = 0.f;
#pragma unroll 8
                for (int b = 0; b < 8; b++)
                    if (b < nb) ls += exp2f(uu[b] - lm);   // -inf -> 0
                for (int off = 32; off > 0; off >>= 1)
                    ls += __shfl_xor(ls, off);
                m = lm; s = ls;
            } else {
                // dense fallback: full row scan (rare; safety valve)
                m = -INFINITY; s = 0.f;
                const halfx8* rowp = (const halfx8*)(M + (size_t)row * N);
                for (int ch = lane; ch < N / 8; ch += 64) {
                    halfx8 sv = rowp[ch];
                    int j0 = ch * 8;
                    float u[8];
#pragma unroll
                    for (int k = 0; k < 8; k++)
                        u[k] = fmaf((float)sv[k], TWO_K,
                                    (sysloadf(pin + j0 + k) - other[j0 + k]) * K_LOG2);
                    float mloc = fmaxf(fmaxf(fmaxf(u[0], u[1]), fmaxf(u[2], u[3])),
                                       fmaxf(fmaxf(u[4], u[5]), fmaxf(u[6], u[7])));
                    float M2 = fmaxf(m, mloc);
                    float acc = 0.f;
#pragma unroll
                    for (int k = 0; k < 8; k++) acc += exp2f(u[k] - M2);
                    s = s * exp2f(m - M2) + acc;
                    m = M2;
                }
                for (int off = 32; off > 0; off >>= 1) {
                    float m2 = __shfl_xor(m, off), s2 = __shfl_xor(s, off);
                    float Mx = fmaxf(m, m2);
                    float a1 = (m  == -INFINITY) ? 0.f : s  * exp2f(m  - Mx);
                    float a2 = (m2 == -INFINITY) ? 0.f : s2 * exp2f(m2 - Mx);
                    m = Mx; s = a1 + a2;
                }
            }
            if (lane == 0) {
                sysstoref(&pout[row],
                          NEG_EPS_LN2 * (m + __log2f(s) - own[row] * K_LOG2)
                          + EPS_NEG_LOGMU);
                prevmax[idx] = m;   // consumed only after kernel-end
            }
        }

        // ---- hierarchical fence-free grid barrier ----
        __syncthreads();            // drains vmcnt: system stores now visible
        if (threadIdx.x == 0)
            __hip_atomic_fetch_add(&bar[(blockIdx.x & (NCTR - 1)) * 32], 1,
                                   __ATOMIC_RELAXED, __HIP_MEMORY_SCOPE_SYSTEM);
        if (blockIdx.x == 0 && wave == 0) {
            int target = PBLOCKS * (pi + 1);
            while (true) {
                int v = (lane < NCTR) ? sysloadi(&bar[lane * 32]) : 0;
                for (int off = 32; off > 0; off >>= 1) v += __shfl_xor(v, off);
                if (v >= target) break;
                __builtin_amdgcn_s_sleep(1);
            }
            if (lane == 0)
                __hip_atomic_store(&bar[GO_OFF], pi + 1,
                                   __ATOMIC_RELAXED, __HIP_MEMORY_SCOPE_SYSTEM);
        }
        if (threadIdx.x == 0) {
            while (sysloadi(&bar[GO_OFF]) < pi + 1)
                __builtin_amdgcn_s_sleep(2);
        }
        __syncthreads();
        asm volatile("" ::: "memory");
    }

    if (do_final && blockIdx.x == 0) {
        float s = 0.f;
        for (int t = threadIdx.x; t < N; t += 256)
            s += (sysloadf(P1 + t) + sysloadf(P0 + t))
               - 0.5f * (sysloadf(P3 + t) + sysloadf(P2 + t))
               - 0.5f * (sysloadf(P5 + t) + sysloadf(P4 + t));
        sb[threadIdx.x] = s;
        __syncthreads();
        for (int off = 128; off > 0; off >>= 1) {
            if (threadIdx.x < off) sb[threadIdx.x] += sb[threadIdx.x + off];
            __syncthreads();
        }
        if (threadIdx.x == 0) {
            float v = sb[0] * (1.0f / 4096.0f);
            out[0] = v > 0.f ? v : 0.f;
        }
    }
}

// ---------- finalize (fallback path) ----------
__global__ void finalize_kernel(const float* __restrict__ fxy, const float* __restrict__ gxy,
                                const float* __restrict__ fxx, const float* __restrict__ gxx,
                                const float* __restrict__ fyy, const float* __restrict__ gyy,
                                float* __restrict__ out) {
    __shared__ float sb[256];
    float s = 0.f;
    for (int t = threadIdx.x; t < N; t += 256)
        s += (fxy[t] + gxy[t]) - 0.5f * (fxx[t] + gxx[t]) - 0.5f * (fyy[t] + gyy[t]);
    sb[threadIdx.x] = s;
    __syncthreads();
    for (int off = 128; off > 0; off >>= 1) {
        if (threadIdx.x < off) sb[threadIdx.x] += sb[threadIdx.x + off];
        __syncthreads();
    }
    if (threadIdx.x == 0) {
        float v = sb[0] * (1.0f / 4096.0f);
        out[0] = v > 0.f ? v : 0.f;
    }
}

extern "C" void kernel_launch(void* const* d_in, const int* in_sizes, int n_in,
                              void* d_out, int out_size, void* d_ws, size_t ws_size,
                              hipStream_t stream) {
    const float* x = (const float*)d_in[0];
    const float* y = (const float*)d_in[1];

    const size_t SZ_S = (size_t)N * N * sizeof(_Float16);   // 32 MiB
    const size_t SZ_B = (size_t)N * D * sizeof(__bf16);     // 4 MiB
    const size_t SZ_CAND = (size_t)6 * N * CAP * sizeof(unsigned int);  // 48 MiB

    char* w = (char*)d_ws;
    _Float16* Sxy  = (_Float16*)w; w += SZ_S;
    _Float16* STxy = (_Float16*)w; w += SZ_S;
    _Float16* Sxx  = (_Float16*)w; w += SZ_S;
    _Float16* Syy  = (_Float16*)w; w += SZ_S;
    __bf16* xb = (__bf16*)w;       w += SZ_B;
    __bf16* yb = (__bf16*)w;       w += SZ_B;
    int* cnt = (int*)w;            w += (size_t)6 * N * sizeof(int);
    float* prevmax = (float*)w;    w += (size_t)6 * N * sizeof(float);
    float* x2 = (float*)w;         w += N * sizeof(float);
    float* y2 = (float*)w;         w += N * sizeof(float);
    float* P[6];
    for (int i = 0; i < 6; i++) { P[i] = (float*)w; w += N * sizeof(float); }
    int* bar = (int*)w;            w += (size_t)2 * BARWIN * sizeof(int);
    unsigned int* cand = (unsigned int*)w; w += SZ_CAND;

    const size_t need = (size_t)(w - (char*)d_ws);
    const bool sparse_ok = (ws_size >= need);

    prep_kernel<<<2048, 256, 0, stream>>>(x, y, xb, yb, x2, y2);

    gemm128_kernel<<<dim3(32, 32), 256, 0, stream>>>(xb, yb, Sxy, STxy, 0);
    gemm128_kernel<<<dim3(32, 32), 256, 0, stream>>>(xb, xb, Sxx, Sxx, 1);
    gemm128_kernel<<<dim3(32, 32), 256, 0, stream>>>(yb, yb, Syy, Syy, 1);

    // zero P[0..5] (6N floats) + both barrier windows, contiguous
    hipMemsetAsync(P[0], 0,
                   (size_t)6 * N * sizeof(float) + (size_t)2 * BARWIN * sizeof(int),
                   stream);

    if (sparse_ok) {
        // fulls p=1..8
        for (int p = 1; p <= 8; p++)
            lse_full3_kernel<0><<<3 * (N / 4), 256, 0, stream>>>(
                Sxy, STxy, Sxx, Syy, x2, y2,
                P[0], P[1], P[2], P[3], P[4], P[5], p & 1, cand, cnt, prevmax);
        // builds p=9,10
        for (int p = 9; p <= 10; p++)
            lse_full3_kernel<1><<<3 * (N / 4), 256, 0, stream>>>(
                Sxy, STxy, Sxx, Syy, x2, y2,
                P[0], P[1], P[2], P[3], P[4], P[5], p & 1, cand, cnt, prevmax);
        // sparse window 1: passes 11..48
        sparse_persist_kernel<<<PBLOCKS, 256, 0, stream>>>(
            Sxy, STxy, Sxx, Syy, x2, y2,
            P[0], P[1], P[2], P[3], P[4], P[5],
            cand, cnt, prevmax, 11, 38, bar, 0, (float*)d_out);
        // rebuild p=49,50
        for (int p = 49; p <= 50; p++)
            lse_full3_kernel<1><<<3 * (N / 4), 256, 0, stream>>>(
                Sxy, STxy, Sxx, Syy, x2, y2,
                P[0], P[1], P[2], P[3], P[4], P[5], p & 1, cand, cnt, prevmax);
        // sparse window 2: passes 51..100, finalize inside
        sparse_persist_kernel<<<PBLOCKS, 256, 0, stream>>>(
            Sxy, STxy, Sxx, Syy, x2, y2,
            P[0], P[1], P[2], P[3], P[4], P[5],
            cand, cnt, prevmax, 51, 50, bar + BARWIN, 1, (float*)d_out);
    } else {
        // dense multi-launch fallback (R7-proven shape)
        for (int p = 1; p <= 100; p++)
            lse_full3_kernel<0><<<3 * (N / 4), 256, 0, stream>>>(
                Sxy, STxy, Sxx, Syy, x2, y2,
                P[0], P[1], P[2], P[3], P[4], P[5], p & 1, cand, cnt, prevmax);
        finalize_kernel<<<1, 256, 0, stream>>>(P[1], P[0], P[3], P[2], P[5], P[4],
                                               (float*)d_out);
    }
}

// Round 12
// 1647.909 us; speedup vs baseline: 2.6710x; 1.1268x over previous
//
#include <hip/hip_runtime.h>
#include <hip/hip_bf16.h>
#include <math.h>

// Problem constants (fixed by reference: x,y are (4096, 512) fp32)
#define N 4096
#define D 512

// log-domain constants (base-2 internally; v_exp_f32/v_log_f32 are base-2)
#define K_LOG2 14.426950408889634f          // (1/eps) * log2(e), eps = 0.1
#define TWO_K  28.853900817779268f          // 2 * K_LOG2
#define NEG_EPS_LN2 (-0.06931471805599453f) // -eps * ln(2)
#define EPS_NEG_LOGMU 0.8317766166719343f   // -eps * log_mu = eps * log(4096)

// Sparse-candidate machinery (R5-R11 proven): entries with u < rowmax - MARGIN
// contribute < 2^-MARGIN; MARGIN=600 covers inter-build potential drift with
// >10x headroom (absmax 0.0 across R5-R11).
#define CAP 512
#define MARGIN 600.0f
#define PBLOCKS 384   // 1.5 blocks/CU -> co-resident by construction
#define PPB 128       // blocks per pair
#define NCTR 32       // distributed arrival counters / go copies (128B apart)
#define PAIRBAR 2048  // ints per pair region: [0..1023] arrivals, [1024..2047] go
#define WINBAR 8192   // ints per window region (3 pairs + done counter @6144)

typedef __bf16   bf16x8 __attribute__((ext_vector_type(8)));
typedef _Float16 halfx8 __attribute__((ext_vector_type(8)));
typedef float    floatx4 __attribute__((ext_vector_type(4)));
typedef unsigned short ushortx8v __attribute__((ext_vector_type(8)));

// System-scope (cache-bypassing, IF-coherent) helpers. Lessons: agent fences
// writeback+invalidate per-XCD L2s (R9, ruinous); single hot atomic/poll lines
// serialize at IF (R10/R11). Protocol: relaxed system atomics for potentials
// only; per-pair hierarchical barrier with spread arrival+go lines.
__device__ __forceinline__ float sysloadf(const float* p) {
    return __hip_atomic_load(p, __ATOMIC_RELAXED, __HIP_MEMORY_SCOPE_SYSTEM);
}
__device__ __forceinline__ void sysstoref(float* p, float v) {
    __hip_atomic_store(p, v, __ATOMIC_RELAXED, __HIP_MEMORY_SCOPE_SYSTEM);
}
__device__ __forceinline__ int sysloadi(const int* p) {
    return __hip_atomic_load(p, __ATOMIC_RELAXED, __HIP_MEMORY_SCOPE_SYSTEM);
}

// ---------- fused prep: fp32 -> bf16 rows + exact fp32 row sqnorms ----------
__global__ __launch_bounds__(256) void prep_kernel(
    const float* __restrict__ x, const float* __restrict__ y,
    __bf16* __restrict__ xb, __bf16* __restrict__ yb,
    float* __restrict__ x2, float* __restrict__ y2) {
    int wave = threadIdx.x >> 6, lane = threadIdx.x & 63;
    int r = blockIdx.x * 4 + wave;            // 0..8191
    const float* src = (r < N) ? x + (size_t)r * D : y + (size_t)(r - N) * D;
    __bf16* dst      = (r < N) ? xb + (size_t)r * D : yb + (size_t)(r - N) * D;
    float* sq        = (r < N) ? x2 + r : y2 + (r - N);
    floatx4 a = *(const floatx4*)(src + lane * 8);
    floatx4 b = *(const floatx4*)(src + lane * 8 + 4);
    bf16x8 v;
    float acc = 0.f;
#pragma unroll
    for (int k = 0; k < 4; k++) {
        v[k] = (__bf16)a[k]; v[4 + k] = (__bf16)b[k];
        acc += a[k] * a[k] + b[k] * b[k];
    }
    *(bf16x8*)(dst + lane * 8) = v;
    for (int off = 32; off > 0; off >>= 1) acc += __shfl_down(acc, off);
    if (lane == 0) *sq = acc;
}

// ---------- 128x128-tile GEMM: out = A @ B^T (fp16), writes tile + transposed tile ----------
// (round-4 proven; sym=1 computes upper-triangle blocks + mirror writes)
__global__ __launch_bounds__(256) void gemm128_kernel(
    const __bf16* __restrict__ A, const __bf16* __restrict__ Bm,
    _Float16* __restrict__ out1, _Float16* __restrict__ out2, int sym) {
    if (sym && blockIdx.x > blockIdx.y) return;
    __shared__ char smem[34816];
    __bf16* ldsA = (__bf16*)smem;           // [128][64] swizzled
    __bf16* ldsB = ldsA + 128 * 64;

    int t = threadIdx.x;
    int w = t >> 6, lane = t & 63;
    int m = lane & 15, q = lane >> 4;
    int wr = w & 1, wc = w >> 1;
    int m0 = blockIdx.x * 128, n0 = blockIdx.y * 128;

    int srow = t >> 1, shalf = t & 1;
    const bf16x8* gA = (const bf16x8*)(A  + (size_t)(m0 + srow) * D + shalf * 32);
    const bf16x8* gB = (const bf16x8*)(Bm + (size_t)(n0 + srow) * D + shalf * 32);

    floatx4 acc[4][4];
#pragma unroll
    for (int i = 0; i < 4; i++)
#pragma unroll
        for (int j = 0; j < 4; j++) acc[i][j] = (floatx4){0.f, 0.f, 0.f, 0.f};

    for (int slab = 0; slab < 8; slab++) {
        bf16x8 va[4], vb[4];
#pragma unroll
        for (int i = 0; i < 4; i++) {
            va[i] = gA[slab * 8 + i];
            vb[i] = gB[slab * 8 + i];
        }
        __syncthreads();
#pragma unroll
        for (int i = 0; i < 4; i++) {
            int cp = (shalf * 4 + i) ^ (srow & 7);
            *(bf16x8*)(ldsA + srow * 64 + cp * 8) = va[i];
            *(bf16x8*)(ldsB + srow * 64 + cp * 8) = vb[i];
        }
        __syncthreads();
#pragma unroll
        for (int kk = 0; kk < 2; kk++) {
            bf16x8 af[4], bfr[4];
#pragma unroll
            for (int mt = 0; mt < 4; mt++) {
                int cp = (kk * 4 + q) ^ (m & 7);
                af[mt]  = *(const bf16x8*)(ldsA + (wr * 64 + mt * 16 + m) * 64 + cp * 8);
                bfr[mt] = *(const bf16x8*)(ldsB + (wc * 64 + mt * 16 + m) * 64 + cp * 8);
            }
#pragma unroll
            for (int mt = 0; mt < 4; mt++)
#pragma unroll
                for (int nt = 0; nt < 4; nt++)
                    acc[mt][nt] = __builtin_amdgcn_mfma_f32_16x16x32_bf16(
                        af[mt], bfr[nt], acc[mt][nt], 0, 0, 0);
        }
    }

    __syncthreads();
    _Float16* et = (_Float16*)smem + w * (64 * 66);
#pragma unroll
    for (int mt = 0; mt < 4; mt++)
#pragma unroll
        for (int nt = 0; nt < 4; nt++)
#pragma unroll
            for (int r = 0; r < 4; r++)
                et[(mt * 16 + q * 4 + r) * 66 + nt * 16 + m] = (_Float16)acc[mt][nt][r];

    int l3 = lane >> 3, c8 = lane & 7;
#pragma unroll
    for (int rr = 0; rr < 8; rr++) {
        int rl = rr * 8 + l3;
        halfx8 v = *(const halfx8*)(et + rl * 66 + c8 * 8);
        *(halfx8*)(out1 + (size_t)(m0 + wr * 64 + rl) * N + n0 + wc * 64 + c8 * 8) = v;
    }
#pragma unroll
    for (int rr = 0; rr < 8; rr++) {
        int rT = rr * 8 + l3;
        halfx8 v;
#pragma unroll
        for (int k = 0; k < 8; k++) v[k] = et[(c8 * 8 + k) * 66 + rT];
        *(halfx8*)(out2 + (size_t)(n0 + wc * 64 + rT) * N + m0 + wr * 64 + c8 * 8) = v;
    }
}

// ---------- full Sinkhorn pass (R7-proven): 3 pairs, 1 row/wave, 3072 blocks ----------
template<int BUILD>
__global__ __launch_bounds__(256) void lse_full3_kernel(
    const _Float16* __restrict__ Sxy, const _Float16* __restrict__ STxy,
    const _Float16* __restrict__ Sxx, const _Float16* __restrict__ Syy,
    const float* __restrict__ x2, const float* __restrict__ y2,
    float* __restrict__ Pxy0, float* __restrict__ Pxy1,
    float* __restrict__ Pxx0, float* __restrict__ Pxx1,
    float* __restrict__ Pyy0, float* __restrict__ Pyy1,
    int odd,
    unsigned int* __restrict__ cand, int* __restrict__ cnt,
    float* __restrict__ prevmax) {
    __shared__ float gykT[8 * 512];
    int pair = blockIdx.x >> 10;
    int blk = blockIdx.x & 1023;
    const _Float16* M;
    const float *own, *other, *pin;
    float* pout;
    if (pair == 0) {
        if (odd) { M = Sxy;  own = x2; other = y2; pin = Pxy0; pout = Pxy1; }
        else     { M = STxy; own = y2; other = x2; pin = Pxy1; pout = Pxy0; }
    } else if (pair == 1) {
        M = Sxx; own = x2; other = x2;
        if (odd) { pin = Pxx0; pout = Pxx1; } else { pin = Pxx1; pout = Pxx0; }
    } else {
        M = Syy; own = y2; other = y2;
        if (odd) { pin = Pyy0; pout = Pyy1; } else { pin = Pyy1; pout = Pyy0; }
    }

    int wave = threadIdx.x >> 6, lane = threadIdx.x & 63;

    {   // stage gykT[(j&7)*512 + (j>>3)] = (pin[j] - other[j]) * K
        const floatx4* pi4 = (const floatx4*)pin;
        const floatx4* so4 = (const floatx4*)other;
        for (int tt = threadIdx.x; tt < N / 4; tt += 256) {
            floatx4 pv = pi4[tt], ov = so4[tt];
            int j = tt * 4;
#pragma unroll
            for (int k2 = 0; k2 < 4; k2++) {
                int jj = j + k2;
                gykT[(jj & 7) * 512 + (jj >> 3)] = (pv[k2] - ov[k2]) * K_LOG2;
            }
        }
    }
    __syncthreads();

    int row = blk * 4 + wave;
    int set = pair * 2 + (odd ? 0 : 1);
    int idx = set * N + row;
    float thr = 0.f;
    size_t cbase = 0;
    int ncand = 0;
    unsigned long long lt_mask = (1ull << lane) - 1ull;
    if (BUILD) { thr = prevmax[idx] - MARGIN; cbase = (size_t)idx * CAP; }

    const halfx8* srow = (const halfx8*)(M + (size_t)row * N);
    float m = -INFINITY, s = 0.f;
#pragma unroll
    for (int c = 0; c < 8; c++) {
        int chunk = c * 64 + lane;
        halfx8 sv = srow[chunk];
        int j0 = chunk * 8;
        float u[8];
#pragma unroll
        for (int k = 0; k < 8; k++)
            u[k] = fmaf((float)sv[k], TWO_K, gykT[k * 512 + chunk]);
        float mloc = fmaxf(fmaxf(fmaxf(u[0], u[1]), fmaxf(u[2], u[3])),
                           fmaxf(fmaxf(u[4], u[5]), fmaxf(u[6], u[7])));
        if (BUILD) {
            if (__ballot(mloc >= thr)) {
                ushortx8v s8 = __builtin_bit_cast(ushortx8v, sv);
#pragma unroll
                for (int k = 0; k < 8; k++) {
                    bool hit = (u[k] >= thr);
                    unsigned long long mask = __ballot(hit);
                    if (hit) {
                        int slot = ncand + __popcll(mask & lt_mask);
                        if (slot < CAP)
                            cand[cbase + slot] = ((unsigned int)(j0 + k) << 16) | (unsigned int)s8[k];
                    }
                    ncand += (int)__popcll(mask);
                }
            }
        }
        float M2 = fmaxf(m, mloc);
        float acc = 0.f;
#pragma unroll
        for (int k = 0; k < 8; k++) acc += exp2f(u[k] - M2);
        s = s * exp2f(m - M2) + acc;
        m = M2;
    }
    for (int off = 32; off > 0; off >>= 1) {
        float m2 = __shfl_down(m, off), s2 = __shfl_down(s, off);
        float Mx = fmaxf(m, m2);
        s = s * exp2f(m - Mx) + s2 * exp2f(m2 - Mx);
        m = Mx;
    }
    if (lane == 0) {
        pout[row] = NEG_EPS_LN2 * (m + __log2f(s) - own[row] * K_LOG2) + EPS_NEG_LOGMU;
        prevmax[idx] = m;
        if (BUILD) cnt[idx] = ncand;
    }
}

// ================= persistent sparse window: per-pair barrier + batched gathers =================
// 384 blocks; 128/pair; wave owns 8 rows. Fast path (1<=cnt<=64, the common
// case): all 8 rows' candidate words loaded cached, then 8 independent
// uncached pin-gathers issued back-to-back (8-deep ILP), then compute+reduce.
// Barrier is per-pair (128 arrivals over 32 counters = 4 RMWs each); leader
// fans go out to 32 copies so each copy has <=4 read-pollers (no hot line).
__global__ __launch_bounds__(256) void sparse_persist_kernel(
    const _Float16* __restrict__ Sxy, const _Float16* __restrict__ STxy,
    const _Float16* __restrict__ Sxx, const _Float16* __restrict__ Syy,
    const float* __restrict__ x2, const float* __restrict__ y2,
    float* __restrict__ P0, float* __restrict__ P1,
    float* __restrict__ P2, float* __restrict__ P3,
    float* __restrict__ P4, float* __restrict__ P5,
    const unsigned int* __restrict__ cand, const int* __restrict__ cnt,
    float* __restrict__ prevmax,
    int p0, int npass, int* __restrict__ bar, int do_final, float* __restrict__ out)
{
    __shared__ float sb[256];
    const int wave = threadIdx.x >> 6, lane = threadIdx.x & 63;
    const int pair = blockIdx.x / PPB;
    const int lb = blockIdx.x - pair * PPB;    // 0..127 within pair

    const float* sqa = (pair == 2) ? y2 : x2;
    const float* sqb = (pair == 1) ? x2 : y2;
    const _Float16* Mrow = (pair == 0) ? Sxy : (pair == 1 ? Sxx : Syy);
    const _Float16* Mcol = (pair == 0) ? STxy : Mrow;
    float* PA = (pair == 0) ? P0 : (pair == 1 ? P2 : P4);   // g buffer
    float* PB = (pair == 0) ? P1 : (pair == 1 ? P3 : P5);   // f buffer
    int* mybar = bar + pair * PAIRBAR;

    for (int pi = 0; pi < npass; pi++) {
        int p = p0 + pi;
        int odd = p & 1;
        const _Float16* M  = odd ? Mrow : Mcol;
        const float* own   = odd ? sqa : sqb;
        const float* other = odd ? sqb : sqa;
        const float* pin   = odd ? PA : PB;
        float* pout        = odd ? PB : PA;
        int set = pair * 2 + (odd ? 0 : 1);

        // ---- fast path: 8 rows, phase-split for gather ILP ----
        int  cc[8];
        unsigned int pk[8];
        float pv[8], ov[8];
        int r0 = lb * 32 + wave * 8;
#pragma unroll
        for (int i = 0; i < 8; i++) cc[i] = cnt[set * N + r0 + i];   // cached
#pragma unroll
        for (int i = 0; i < 8; i++) {
            pk[i] = 0;
            if (cc[i] >= 1 && cc[i] <= 64 && lane < cc[i])
                pk[i] = cand[(size_t)(set * N + r0 + i) * CAP + lane];   // cached
        }
#pragma unroll
        for (int i = 0; i < 8; i++) {       // 8 independent uncached gathers
            pv[i] = 0.f;
            if (cc[i] >= 1 && cc[i] <= 64 && lane < cc[i])
                pv[i] = sysloadf(pin + (pk[i] >> 16));
        }
#pragma unroll
        for (int i = 0; i < 8; i++) {       // cached gathers (L1-hot 16KB)
            ov[i] = 0.f;
            if (cc[i] >= 1 && cc[i] <= 64 && lane < cc[i])
                ov[i] = other[pk[i] >> 16];
        }
#pragma unroll
        for (int i = 0; i < 8; i++) {
            if (cc[i] >= 1 && cc[i] <= 64) {
                _Float16 h = __builtin_bit_cast(_Float16, (unsigned short)(pk[i] & 0xffffu));
                float u = (lane < cc[i])
                        ? fmaf((float)h, TWO_K, (pv[i] - ov[i]) * K_LOG2)
                        : -INFINITY;
                float lm = u;
                for (int off = 32; off > 0; off >>= 1)
                    lm = fmaxf(lm, __shfl_xor(lm, off));
                float e = exp2f(u - lm);     // idle lanes: exp2(-inf)=0
                for (int off = 32; off > 0; off >>= 1)
                    e += __shfl_xor(e, off);
                if (lane == 0) {
                    int row = r0 + i;
                    sysstoref(&pout[row],
                              NEG_EPS_LN2 * (lm + __log2f(e) - own[row] * K_LOG2)
                              + EPS_NEG_LOGMU);
                    prevmax[set * N + row] = lm;
                }
            }
        }
        // ---- slow rows (cnt>64 batched; cnt==0 or >CAP dense fallback) ----
        for (int i = 0; i < 8; i++) {
            int c = cc[i];
            if (c >= 1 && c <= 64) continue;
            int row = r0 + i;
            int idx = set * N + row;
            float m, s;
            if (c > 64 && c <= CAP) {
                size_t cbase = (size_t)idx * CAP;
                int nb = (c + 63) >> 6;
                float uu[8];
                float lm = -INFINITY;
#pragma unroll 8
                for (int b = 0; b < 8; b++) {
                    uu[b] = -INFINITY;
                    if (b < nb) {
                        int t = b * 64 + lane;
                        if (t < c) {
                            unsigned int w = cand[cbase + t];
                            int j = w >> 16;
                            _Float16 h = __builtin_bit_cast(_Float16, (unsigned short)(w & 0xffffu));
                            uu[b] = fmaf((float)h, TWO_K,
                                         (sysloadf(pin + j) - other[j]) * K_LOG2);
                        }
                        lm = fmaxf(lm, uu[b]);
                    }
                }
                for (int off = 32; off > 0; off >>= 1)
                    lm = fmaxf(lm, __shfl_xor(lm, off));
                float ls = 0.f;
#pragma unroll 8
                for (int b = 0; b < 8; b++)
                    if (b < nb) ls += exp2f(uu[b] - lm);
                for (int off = 32; off > 0; off >>= 1)
                    ls += __shfl_xor(ls, off);
                m = lm; s = ls;
            } else {
                // dense fallback: full row scan (rare; safety valve)
                m = -INFINITY; s = 0.f;
                const halfx8* rowp = (const halfx8*)(M + (size_t)row * N);
                for (int ch = lane; ch < N / 8; ch += 64) {
                    halfx8 sv = rowp[ch];
                    int j0 = ch * 8;
                    float u[8];
#pragma unroll
                    for (int k = 0; k < 8; k++)
                        u[k] = fmaf((float)sv[k], TWO_K,
                                    (sysloadf(pin + j0 + k) - other[j0 + k]) * K_LOG2);
                    float mloc = fmaxf(fmaxf(fmaxf(u[0], u[1]), fmaxf(u[2], u[3])),
                                       fmaxf(fmaxf(u[4], u[5]), fmaxf(u[6], u[7])));
                    float M2 = fmaxf(m, mloc);
                    float acc = 0.f;
#pragma unroll
                    for (int k = 0; k < 8; k++) acc += exp2f(u[k] - M2);
                    s = s * exp2f(m - M2) + acc;
                    m = M2;
                }
                for (int off = 32; off > 0; off >>= 1) {
                    float m2 = __shfl_xor(m, off), s2 = __shfl_xor(s, off);
                    float Mx = fmaxf(m, m2);
                    float a1 = (m  == -INFINITY) ? 0.f : s  * exp2f(m  - Mx);
                    float a2 = (m2 == -INFINITY) ? 0.f : s2 * exp2f(m2 - Mx);
                    m = Mx; s = a1 + a2;
                }
            }
            if (lane == 0) {
                sysstoref(&pout[row],
                          NEG_EPS_LN2 * (m + __log2f(s) - own[row] * K_LOG2)
                          + EPS_NEG_LOGMU);
                prevmax[idx] = m;
            }
        }

        // ---- per-pair hierarchical barrier (no fences, no hot lines) ----
        __syncthreads();            // drains vmcnt: system stores now visible
        if (threadIdx.x == 0)
            __hip_atomic_fetch_add(&mybar[(lb & (NCTR - 1)) * 32], 1,
                                   __ATOMIC_RELAXED, __HIP_MEMORY_SCOPE_SYSTEM);
        if (lb == 0 && wave == 0) {
            int target = PPB * (pi + 1);
            while (true) {
                int v = (lane < NCTR) ? sysloadi(&mybar[lane * 32]) : 0;
#pragma unroll
                for (int off = 32; off > 0; off >>= 1) v += __shfl_xor(v, off);
                if (v >= target) break;
                __builtin_amdgcn_s_sleep(1);
            }
            if (lane < NCTR)
                __hip_atomic_store(&mybar[1024 + lane * 32], pi + 1,
                                   __ATOMIC_RELAXED, __HIP_MEMORY_SCOPE_SYSTEM);
        }
        if (threadIdx.x == 0) {
            const int* go = &mybar[1024 + (lb & (NCTR - 1)) * 32];
            while (sysloadi(go) < pi + 1)
                __builtin_amdgcn_s_sleep(8);
        }
        __syncthreads();
        asm volatile("" ::: "memory");
    }

    // pair-done handshake (window-scoped) for cross-pair finalize ordering
    if (threadIdx.x == 0 && lb == 0)
        __hip_atomic_fetch_add(&bar[3 * PAIRBAR], 1,
                               __ATOMIC_RELAXED, __HIP_MEMORY_SCOPE_SYSTEM);

    if (do_final && blockIdx.x == 0) {
        if (threadIdx.x == 0) {
            while (sysloadi(&bar[3 * PAIRBAR]) < 3)
                __builtin_amdgcn_s_sleep(8);
        }
        __syncthreads();
        float s = 0.f;
        for (int t = threadIdx.x; t < N; t += 256)
            s += (sysloadf(P1 + t) + sysloadf(P0 + t))
               - 0.5f * (sysloadf(P3 + t) + sysloadf(P2 + t))
               - 0.5f * (sysloadf(P5 + t) + sysloadf(P4 + t));
        sb[threadIdx.x] = s;
        __syncthreads();
        for (int off = 128; off > 0; off >>= 1) {
            if (threadIdx.x < off) sb[threadIdx.x] += sb[threadIdx.x + off];
            __syncthreads();
        }
        if (threadIdx.x == 0) {
            float v = sb[0] * (1.0f / 4096.0f);
            out[0] = v > 0.f ? v : 0.f;
        }
    }
}

// ---------- finalize (fallback path) ----------
__global__ void finalize_kernel(const float* __restrict__ fxy, const float* __restrict__ gxy,
                                const float* __restrict__ fxx, const float* __restrict__ gxx,
                                const float* __restrict__ fyy, const float* __restrict__ gyy,
                                float* __restrict__ out) {
    __shared__ float sb[256];
    float s = 0.f;
    for (int t = threadIdx.x; t < N; t += 256)
        s += (fxy[t] + gxy[t]) - 0.5f * (fxx[t] + gxx[t]) - 0.5f * (fyy[t] + gyy[t]);
    sb[threadIdx.x] = s;
    __syncthreads();
    for (int off = 128; off > 0; off >>= 1) {
        if (threadIdx.x < off) sb[threadIdx.x] += sb[threadIdx.x + off];
        __syncthreads();
    }
    if (threadIdx.x == 0) {
        float v = sb[0] * (1.0f / 4096.0f);
        out[0] = v > 0.f ? v : 0.f;
    }
}

extern "C" void kernel_launch(void* const* d_in, const int* in_sizes, int n_in,
                              void* d_out, int out_size, void* d_ws, size_t ws_size,
                              hipStream_t stream) {
    const float* x = (const float*)d_in[0];
    const float* y = (const float*)d_in[1];

    const size_t SZ_S = (size_t)N * N * sizeof(_Float16);   // 32 MiB
    const size_t SZ_B = (size_t)N * D * sizeof(__bf16);     // 4 MiB
    const size_t SZ_CAND = (size_t)6 * N * CAP * sizeof(unsigned int);  // 48 MiB

    char* w = (char*)d_ws;
    _Float16* Sxy  = (_Float16*)w; w += SZ_S;
    _Float16* STxy = (_Float16*)w; w += SZ_S;
    _Float16* Sxx  = (_Float16*)w; w += SZ_S;
    _Float16* Syy  = (_Float16*)w; w += SZ_S;
    __bf16* xb = (__bf16*)w;       w += SZ_B;
    __bf16* yb = (__bf16*)w;       w += SZ_B;
    int* cnt = (int*)w;            w += (size_t)6 * N * sizeof(int);
    float* prevmax = (float*)w;    w += (size_t)6 * N * sizeof(float);
    float* x2 = (float*)w;         w += N * sizeof(float);
    float* y2 = (float*)w;         w += N * sizeof(float);
    float* P[6];
    for (int i = 0; i < 6; i++) { P[i] = (float*)w; w += N * sizeof(float); }
    int* bar = (int*)w;            w += (size_t)2 * WINBAR * sizeof(int);
    unsigned int* cand = (unsigned int*)w; w += SZ_CAND;

    const size_t need = (size_t)(w - (char*)d_ws);
    const bool sparse_ok = (ws_size >= need);

    prep_kernel<<<2048, 256, 0, stream>>>(x, y, xb, yb, x2, y2);

    gemm128_kernel<<<dim3(32, 32), 256, 0, stream>>>(xb, yb, Sxy, STxy, 0);
    gemm128_kernel<<<dim3(32, 32), 256, 0, stream>>>(xb, xb, Sxx, Sxx, 1);
    gemm128_kernel<<<dim3(32, 32), 256, 0, stream>>>(yb, yb, Syy, Syy, 1);

    // zero P[0..5] (6N floats) + both barrier windows, contiguous
    hipMemsetAsync(P[0], 0,
                   (size_t)6 * N * sizeof(float) + (size_t)2 * WINBAR * sizeof(int),
                   stream);

    if (sparse_ok) {
        // fulls p=1..8
        for (int p = 1; p <= 8; p++)
            lse_full3_kernel<0><<<3 * (N / 4), 256, 0, stream>>>(
                Sxy, STxy, Sxx, Syy, x2, y2,
                P[0], P[1], P[2], P[3], P[4], P[5], p & 1, cand, cnt, prevmax);
        // builds p=9,10
        for (int p = 9; p <= 10; p++)
            lse_full3_kernel<1><<<3 * (N / 4), 256, 0, stream>>>(
                Sxy, STxy, Sxx, Syy, x2, y2,
                P[0], P[1], P[2], P[3], P[4], P[5], p & 1, cand, cnt, prevmax);
        // sparse window 1: passes 11..48
        sparse_persist_kernel<<<PBLOCKS, 256, 0, stream>>>(
            Sxy, STxy, Sxx, Syy, x2, y2,
            P[0], P[1], P[2], P[3], P[4], P[5],
            cand, cnt, prevmax, 11, 38, bar, 0, (float*)d_out);
        // rebuild p=49,50
        for (int p = 49; p <= 50; p++)
            lse_full3_kernel<1><<<3 * (N / 4), 256, 0, stream>>>(
                Sxy, STxy, Sxx, Syy, x2, y2,
                P[0], P[1], P[2], P[3], P[4], P[5], p & 1, cand, cnt, prevmax);
        // sparse window 2: passes 51..100, finalize inside
        sparse_persist_kernel<<<PBLOCKS, 256, 0, stream>>>(
            Sxy, STxy, Sxx, Syy, x2, y2,
            P[0], P[1], P[2], P[3], P[4], P[5],
            cand, cnt, prevmax, 51, 50, bar + WINBAR, 1, (float*)d_out);
    } else {
        // dense multi-launch fallback (R7-proven shape)
        for (int p = 1; p <= 100; p++)
            lse_full3_kernel<0><<<3 * (N / 4), 256, 0, stream>>>(
                Sxy, STxy, Sxx, Syy, x2, y2,
                P[0], P[1], P[2], P[3], P[4], P[5], p & 1, cand, cnt, prevmax);
        finalize_kernel<<<1, 256, 0, stream>>>(P[1], P[0], P[3], P[2], P[5], P[4],
                                               (float*)d_out);
    }
}